// Round 12
// baseline (590.248 us; speedup 1.0000x reference)
//
#include <hip/hip_runtime.h>

#define NN 50000
#define NE 800000
#define NG 2000
#define BN_EPS 1e-5f
#define NB_SCAN 196   // ceil(NN/256)
#define NCHUNK 50000  // NE/16

typedef __attribute__((ext_vector_type(8))) short bf16x8;
typedef __attribute__((ext_vector_type(4))) float f32x4;

__device__ __forceinline__ float lrelu(float v) { return v > 0.f ? v : 0.01f * v; }

__device__ __forceinline__ unsigned short f2bf(float x) {
    union { float f; unsigned u; } v; v.f = x;
    unsigned r = v.u + 0x7FFF + ((v.u >> 16) & 1);
    return (unsigned short)(r >> 16);
}
__device__ __forceinline__ float bf2f(unsigned short h) {
    union { unsigned u; float f; } v; v.u = ((unsigned)h) << 16;
    return v.f;
}
__device__ __forceinline__ bf16x8 u4_to_bf(uint4 u) {
    union { uint4 q; bf16x8 b; } c; c.q = u; return c.b;
}

// ---- zero pool+cstats+stats+cnt
__global__ __launch_bounds__(256) void k_prep(int* __restrict__ p, int n)
{
    int tid = blockIdx.x * 256 + threadIdx.x;
    for (int i = tid; i < n; i += gridDim.x * 256) p[i] = 0;
}

// ---- convert + transpose GEMM weights to split bf16 (hi+lo) [N][K]
__global__ __launch_bounds__(256) void k_wcvt(
    const float* __restrict__ W1, const float* __restrict__ W2,
    const float* __restrict__ cW1, const float* __restrict__ cW2,
    unsigned short* __restrict__ w1h, unsigned short* __restrict__ w1l,
    unsigned short* __restrict__ w2h, unsigned short* __restrict__ w2l,
    unsigned short* __restrict__ cw1h, unsigned short* __restrict__ cw1l,
    unsigned short* __restrict__ cw2h, unsigned short* __restrict__ cw2l)
{
    int b = blockIdx.x, t = threadIdx.x;
    if (b < 6) {
        const float* s = (b < 3) ? (W1 + b * 4096) : (W2 + (b - 3) * 4096);
        unsigned short* dh = (b < 3) ? (w1h + b * 4096) : (w2h + (b - 3) * 4096);
        unsigned short* dl = (b < 3) ? (w1l + b * 4096) : (w2l + (b - 3) * 4096);
        for (int i = t; i < 4096; i += 256) {
            int k = i >> 6, n = i & 63;
            float v = s[i];
            unsigned short h = f2bf(v);
            dh[n * 64 + k] = h;
            dl[n * 64 + k] = f2bf(v - bf2f(h));
        }
    } else {
        const float* s = (b == 6) ? cW1 : cW2;
        unsigned short* dh = (b == 6) ? cw1h : cw2h;
        unsigned short* dl = (b == 6) ? cw1l : cw2l;
        for (int i = t; i < 16384; i += 256) {
            int k = i >> 7, n = i & 127;
            float v = s[i];
            unsigned short h = f2bf(v);
            dh[n * 128 + k] = h;
            dl[n * 128 + k] = f2bf(v - bf2f(h));
        }
    }
}

// ---- histogram of dst
__global__ __launch_bounds__(256) void k_hist(const int* __restrict__ dst, int* __restrict__ cnt)
{
    int tid = blockIdx.x * 256 + threadIdx.x;
    for (int e = tid; e < NE; e += gridDim.x * 256) atomicAdd(&cnt[dst[e]], 1);
}

__global__ __launch_bounds__(256) void k_scanA(const int* __restrict__ cnt,
    int* __restrict__ off, int* __restrict__ bsum)
{
    __shared__ int s[256];
    int t = threadIdx.x;
    int i = blockIdx.x * 256 + t;
    int v = (i < NN) ? cnt[i] : 0;
    s[t] = v; __syncthreads();
    #pragma unroll
    for (int d = 1; d < 256; d <<= 1) {
        int u = (t >= d) ? s[t - d] : 0;
        __syncthreads();
        s[t] += u;
        __syncthreads();
    }
    if (i < NN) off[i + 1] = s[t];
    if (t == 255) bsum[blockIdx.x] = s[255];
}

__global__ __launch_bounds__(256) void k_scanB(const int* __restrict__ bsum, int* __restrict__ boff)
{
    __shared__ int s[256];
    int t = threadIdx.x;
    int v = (t < NB_SCAN) ? bsum[t] : 0;
    s[t] = v; __syncthreads();
    #pragma unroll
    for (int d = 1; d < 256; d <<= 1) {
        int u = (t >= d) ? s[t - d] : 0;
        __syncthreads();
        s[t] += u;
        __syncthreads();
    }
    boff[t] = s[t] - v;
}

__global__ __launch_bounds__(256) void k_scanC(const int* __restrict__ cnt,
    int* __restrict__ off, const int* __restrict__ boff, int* __restrict__ cur)
{
    int i = blockIdx.x * 256 + threadIdx.x;
    if (i < NN) {
        int incl = off[i + 1] + boff[blockIdx.x];
        off[i + 1] = incl;
        cur[i] = incl - cnt[i];
    }
    if (i == 0) off[0] = 0;
}

// ---- scatter perm only (4B random writes into L2-resident 3.2MB buffer)
__global__ __launch_bounds__(256) void k_scatterP(
    const int* __restrict__ dst, int* __restrict__ cur, int* __restrict__ perm)
{
    int tid = blockIdx.x * 256 + threadIdx.x;
    for (int e = tid; e < NE; e += gridDim.x * 256) {
        int p = atomicAdd(&cur[dst[e]], 1);
        perm[p] = e;
    }
}

// ---- sds[p] = pack(src[perm[p]], dst[perm[p]]) — sequential writes, random 4B reads
__global__ __launch_bounds__(256) void k_sds(
    const int* __restrict__ src, const int* __restrict__ dst,
    const int* __restrict__ perm, unsigned* __restrict__ sds)
{
    int tid = blockIdx.x * 256 + threadIdx.x;
    for (int p = tid; p < NE; p += gridDim.x * 256) {
        int e = perm[p];
        sds[p] = (unsigned)src[e] | ((unsigned)dst[e] << 16);
    }
}

// ---- aggr = (1+eps[l]) * x  (layer 0 only; later layers fused into k_bn2)
__global__ __launch_bounds__(256) void k_init(const float* __restrict__ x,
    const float* __restrict__ eps, int layer, float* __restrict__ aggr)
{
    int tid = blockIdx.x * 256 + threadIdx.x;
    float s = 1.f + eps[layer];
    const float4* xv = (const float4*)x;
    float4* av = (float4*)aggr;
    for (int i = tid; i < NN * 16; i += gridDim.x * 256) {
        float4 v = xv[i];
        v.x *= s; v.y *= s; v.z *= s; v.w *= s;
        av[i] = v;
    }
}

// ---- MFMA edge aggregation: wave owns 8 chunks x 16 sorted edges.
// ea read through perm (fp32), converted to split-bf16 in registers.
__global__ __launch_bounds__(256) void k_aggr_m(
    const float* __restrict__ x, const float* __restrict__ ea,
    const int* __restrict__ perm, const unsigned* __restrict__ sds,
    const float* __restrict__ We, const float* __restrict__ be,
    float* __restrict__ aggr)
{
    __shared__ unsigned short wth[1024], wtl[1024];  // [col][k] transposed We hi/lo
    __shared__ float els[4 * 16 * 65];               // per-wave e' tile [16 edges][65]
    int t = threadIdx.x;
    for (int i = t; i < 1024; i += 256) {
        int col = i >> 4, k = i & 15;
        float v = We[k * 64 + col];
        unsigned short h = f2bf(v);
        wth[col * 16 + k] = h;
        wtl[col * 16 + k] = f2bf(v - bf2f(h));
    }
    __syncthreads();

    int lane = t & 63, w = t >> 6;
    float* myels = els + w * (16 * 65);
    int ar = lane & 15;
    int kg = (lane >> 4) & 1;
    bool klive = lane < 32;

    bf16x8 bh[4], bl[4];
    float bias4[4];
    #pragma unroll
    for (int nc = 0; nc < 4; ++nc) {
        int col = nc * 16 + ar;
        uint4 hv = {0, 0, 0, 0}, lv = {0, 0, 0, 0};
        if (klive) {
            hv = *(const uint4*)(wth + col * 16 + kg * 8);
            lv = *(const uint4*)(wtl + col * 16 + kg * 8);
        }
        bh[nc] = u4_to_bf(hv);
        bl[nc] = u4_to_bf(lv);
        bias4[nc] = be[col];
    }

    int cbase0 = (blockIdx.x * 4 + w) * 8;
    for (int ci = 0; ci < 8; ++ci) {
        int chunk = cbase0 + ci;
        if (chunk >= NCHUNK) break;
        int e0 = chunk * 16;

        // coalesced: packed (src,dst) for the 16 edges
        unsigned sdw = sds[e0 + ar];
        int sl = (int)(sdw & 0xFFFFu);
        int dl = (int)(sdw >> 16);

        // issue x gathers early (independent of ea chain)
        float xv[16];
        #pragma unroll
        for (int e = 0; e < 16; ++e) {
            int s_e = __builtin_amdgcn_readlane(sl, e);
            xv[e] = x[(size_t)s_e * 64 + lane];
        }

        // ea via perm, convert fp32 -> split bf16 in registers
        uint4 hv = {0, 0, 0, 0}, lv = {0, 0, 0, 0};
        if (klive) {
            int eidx = perm[e0 + ar];
            const float* ap = ea + (size_t)eidx * 16 + kg * 8;
            float4 u0 = *(const float4*)ap;
            float4 u1 = *(const float4*)(ap + 4);
            float vv[8] = {u0.x, u0.y, u0.z, u0.w, u1.x, u1.y, u1.z, u1.w};
            unsigned hw[4], lw[4];
            #pragma unroll
            for (int j = 0; j < 4; ++j) {
                unsigned short h0 = f2bf(vv[2 * j]), h1 = f2bf(vv[2 * j + 1]);
                hw[j] = (unsigned)h0 | ((unsigned)h1 << 16);
                lw[j] = (unsigned)f2bf(vv[2 * j] - bf2f(h0))
                      | ((unsigned)f2bf(vv[2 * j + 1] - bf2f(h1)) << 16);
            }
            hv.x = hw[0]; hv.y = hw[1]; hv.z = hw[2]; hv.w = hw[3];
            lv.x = lw[0]; lv.y = lw[1]; lv.z = lw[2]; lv.w = lw[3];
        }
        bf16x8 ah = u4_to_bf(hv), al = u4_to_bf(lv);

        #pragma unroll
        for (int nc = 0; nc < 4; ++nc) {
            f32x4 acc;
            acc[0] = bias4[nc]; acc[1] = bias4[nc]; acc[2] = bias4[nc]; acc[3] = bias4[nc];
            acc = __builtin_amdgcn_mfma_f32_16x16x32_bf16(ah, bh[nc], acc, 0, 0, 0);
            acc = __builtin_amdgcn_mfma_f32_16x16x32_bf16(al, bh[nc], acc, 0, 0, 0);
            acc = __builtin_amdgcn_mfma_f32_16x16x32_bf16(ah, bl[nc], acc, 0, 0, 0);
            int rbase = (lane >> 4) * 4;
            #pragma unroll
            for (int r = 0; r < 4; ++r)
                myels[(rbase + r) * 65 + nc * 16 + ar] = acc[r];
        }

        int d = __builtin_amdgcn_readlane(dl, 0);
        float acc = 0.f;
        #pragma unroll
        for (int e = 0; e < 16; ++e) {
            float m = xv[e] + myels[e * 65 + lane];
            m = fmaxf(m, 0.f);
            acc += m;
            int dn = (e < 15) ? __builtin_amdgcn_readlane(dl, e + 1) : -1;
            if (dn != d) {
                atomicAdd(&aggr[(size_t)d * 64 + lane], acc);
                acc = 0.f;
                d = dn;
            }
        }
    }
}

// ---- split-bf16 MFMA [N,64]@Wt+b. PRE: BN+lrelu input. POST0: raw+stats. POST1: lrelu (+pool).
template<int PRE, int POST>
__global__ __launch_bounds__(256) void k_mm64_f(
    const float* __restrict__ in,
    const unsigned short* __restrict__ Wh, const unsigned short* __restrict__ Wl,
    const float* __restrict__ bias, const float* __restrict__ statsIn,
    const float* __restrict__ gIn, const float* __restrict__ bIn,
    float* __restrict__ out, float* __restrict__ statsOut,
    const int* __restrict__ batch, float* __restrict__ pool)
{
    __shared__ unsigned short Ash[64 * 64], Asl[64 * 64];
    __shared__ unsigned short Bsh[64 * 64], Bsl[64 * 64];
    __shared__ float sc[64], sh[64];
    __shared__ float red[4 * 128];
    int t = threadIdx.x;
    int base = blockIdx.x * 64;
    if (PRE && t < 64) {
        float m = statsIn[t] * (1.f / NN);
        float v = statsIn[64 + t] * (1.f / NN) - m * m;
        float s = gIn[t] * rsqrtf(v + BN_EPS);
        sc[t] = s; sh[t] = bIn[t] - m * s;
    }
    for (int i = t; i < 512; i += 256) {
        int n = i >> 3, cb = i & 7;
        ((uint4*)Bsh)[n * 8 + (cb ^ (n & 7))] = ((const uint4*)Wh)[i];
        ((uint4*)Bsl)[n * 8 + (cb ^ (n & 7))] = ((const uint4*)Wl)[i];
    }
    __syncthreads();
    for (int i = t; i < 512; i += 256) {
        int row = i >> 3, cb = i & 7;
        int node = base + row;
        float v[8] = {0.f, 0.f, 0.f, 0.f, 0.f, 0.f, 0.f, 0.f};
        if (node < NN) {
            float4 u0 = *(const float4*)(in + (size_t)node * 64 + cb * 8);
            float4 u1 = *(const float4*)(in + (size_t)node * 64 + cb * 8 + 4);
            v[0] = u0.x; v[1] = u0.y; v[2] = u0.z; v[3] = u0.w;
            v[4] = u1.x; v[5] = u1.y; v[6] = u1.z; v[7] = u1.w;
            if (PRE) {
                #pragma unroll
                for (int j = 0; j < 8; ++j) {
                    int c = cb * 8 + j;
                    v[j] = lrelu(fmaf(v[j], sc[c], sh[c]));
                }
            }
        }
        unsigned hw[4], lw[4];
        #pragma unroll
        for (int j = 0; j < 4; ++j) {
            unsigned short h0 = f2bf(v[2 * j]), h1 = f2bf(v[2 * j + 1]);
            unsigned short l0 = f2bf(v[2 * j] - bf2f(h0)), l1 = f2bf(v[2 * j + 1] - bf2f(h1));
            hw[j] = (unsigned)h0 | ((unsigned)h1 << 16);
            lw[j] = (unsigned)l0 | ((unsigned)l1 << 16);
        }
        uint4 rh = { hw[0], hw[1], hw[2], hw[3] };
        uint4 rl = { lw[0], lw[1], lw[2], lw[3] };
        int idx = row * 8 + (cb ^ (row & 7));
        ((uint4*)Ash)[idx] = rh;
        ((uint4*)Asl)[idx] = rl;
    }
    __syncthreads();

    int w = t >> 6, l = t & 63;
    int ar = l & 15, kg = l >> 4;
    bf16x8 afh[2], afl[2];
    #pragma unroll
    for (int kt = 0; kt < 2; ++kt) {
        int row = w * 16 + ar, cb = kt * 4 + kg;
        int idx = row * 8 + (cb ^ (row & 7));
        afh[kt] = ((const bf16x8*)Ash)[idx];
        afl[kt] = ((const bf16x8*)Asl)[idx];
    }
    f32x4 acc[4];
    #pragma unroll
    for (int nt = 0; nt < 4; ++nt) { acc[nt][0] = 0.f; acc[nt][1] = 0.f; acc[nt][2] = 0.f; acc[nt][3] = 0.f; }
    #pragma unroll
    for (int nt = 0; nt < 4; ++nt) {
        #pragma unroll
        for (int kt = 0; kt < 2; ++kt) {
            int n = nt * 16 + ar, cb = kt * 4 + kg;
            int idx = n * 8 + (cb ^ (n & 7));
            bf16x8 bfh = ((const bf16x8*)Bsh)[idx];
            bf16x8 bfl = ((const bf16x8*)Bsl)[idx];
            acc[nt] = __builtin_amdgcn_mfma_f32_16x16x32_bf16(afh[kt], bfh, acc[nt], 0, 0, 0);
            acc[nt] = __builtin_amdgcn_mfma_f32_16x16x32_bf16(afl[kt], bfh, acc[nt], 0, 0, 0);
            acc[nt] = __builtin_amdgcn_mfma_f32_16x16x32_bf16(afh[kt], bfl, acc[nt], 0, 0, 0);
        }
    }
    int rb = base + w * 16 + kg * 4;
    int bidx[4];
    if (POST == 1) {
        #pragma unroll
        for (int r = 0; r < 4; ++r)
            bidx[r] = (rb + r < NN) ? batch[rb + r] : 0;
    }
    #pragma unroll
    for (int nt = 0; nt < 4; ++nt) {
        int col = nt * 16 + ar;
        float bv = bias[col];
        float s = 0.f, q = 0.f;
        #pragma unroll
        for (int r = 0; r < 4; ++r) {
            int node = rb + r;
            float d = acc[nt][r] + bv;
            if (POST == 1) d = lrelu(d);
            if (node < NN) {
                out[(size_t)node * 64 + col] = d;
                if (POST == 1)
                    atomicAdd(&pool[(size_t)bidx[r] * 64 + col], d);
            }
            if (POST == 0) {
                d = (node < NN) ? d : 0.f;
                s += d; q += d * d;
            }
        }
        if (POST == 0) {
            s += __shfl_xor(s, 16); s += __shfl_xor(s, 32);
            q += __shfl_xor(q, 16); q += __shfl_xor(q, 32);
            if (kg == 0) { red[w * 128 + col] = s; red[w * 128 + 64 + col] = q; }
        }
    }
    if (POST == 0) {
        __syncthreads();
        if (t < 128) {
            int c = t & 63, which = t >> 6;
            float v = red[0 * 128 + which * 64 + c] + red[1 * 128 + which * 64 + c]
                    + red[2 * 128 + which * 64 + c] + red[3 * 128 + which * 64 + c];
            atomicAdd(&statsOut[which * 64 + c], v);
        }
    }
}

// ---- split-bf16 MFMA [N,128]@Wt+b, 64-col blocks.
template<int MODE>
__global__ __launch_bounds__(256) void k_cmm_f(
    const float* __restrict__ inA, const float* __restrict__ pool,
    const int* __restrict__ batch, const float* __restrict__ statsIn,
    const float* __restrict__ gIn, const float* __restrict__ bIn,
    const unsigned short* __restrict__ Wh, const unsigned short* __restrict__ Wl,
    const float* __restrict__ bias,
    float* __restrict__ out, float* __restrict__ statsOut)
{
    __shared__ unsigned short Ash[64 * 128], Asl[64 * 128];
    __shared__ unsigned short Bsh[64 * 128], Bsl[64 * 128];
    __shared__ float sc[128], sh[128];
    __shared__ float red[4 * 128];
    int t = threadIdx.x;
    int base = (blockIdx.x >> 1) * 64;
    int ncol0 = (blockIdx.x & 1) * 64;
    if (MODE == 1 && t < 128) {
        float m = statsIn[t] * (1.f / NN);
        float v = statsIn[128 + t] * (1.f / NN) - m * m;
        float s = gIn[t] * rsqrtf(v + BN_EPS);
        sc[t] = s; sh[t] = bIn[t] - m * s;
    }
    for (int i = t; i < 1024; i += 256) {
        int n = i >> 4, cb = i & 15;
        int idx = n * 16 + (cb ^ (n & 7));
        ((uint4*)Bsh)[idx] = ((const uint4*)Wh)[(ncol0 + n) * 16 + cb];
        ((uint4*)Bsl)[idx] = ((const uint4*)Wl)[(ncol0 + n) * 16 + cb];
    }
    __syncthreads();
    for (int i = t; i < 1024; i += 256) {
        int row = i >> 4, cb = i & 15;
        int node = base + row;
        float v[8] = {0.f, 0.f, 0.f, 0.f, 0.f, 0.f, 0.f, 0.f};
        if (node < NN) {
            const float* sp;
            if (MODE == 0) {
                sp = (cb < 8) ? (inA + (size_t)node * 64 + cb * 8)
                              : (pool + (size_t)batch[node] * 64 + (cb - 8) * 8);
            } else {
                sp = inA + (size_t)node * 128 + cb * 8;
            }
            float4 u0 = *(const float4*)sp;
            float4 u1 = *(const float4*)(sp + 4);
            v[0] = u0.x; v[1] = u0.y; v[2] = u0.z; v[3] = u0.w;
            v[4] = u1.x; v[5] = u1.y; v[6] = u1.z; v[7] = u1.w;
            if (MODE == 1) {
                #pragma unroll
                for (int j = 0; j < 8; ++j) {
                    int c = cb * 8 + j;
                    v[j] = lrelu(fmaf(v[j], sc[c], sh[c]));
                }
            }
        }
        unsigned hw[4], lw[4];
        #pragma unroll
        for (int j = 0; j < 4; ++j) {
            unsigned short h0 = f2bf(v[2 * j]), h1 = f2bf(v[2 * j + 1]);
            unsigned short l0 = f2bf(v[2 * j] - bf2f(h0)), l1 = f2bf(v[2 * j + 1] - bf2f(h1));
            hw[j] = (unsigned)h0 | ((unsigned)h1 << 16);
            lw[j] = (unsigned)l0 | ((unsigned)l1 << 16);
        }
        uint4 rh = { hw[0], hw[1], hw[2], hw[3] };
        uint4 rl = { lw[0], lw[1], lw[2], lw[3] };
        int idx = row * 16 + (cb ^ (row & 7));
        ((uint4*)Ash)[idx] = rh;
        ((uint4*)Asl)[idx] = rl;
    }
    __syncthreads();

    int w = t >> 6, l = t & 63;
    int ar = l & 15, kg = l >> 4;
    bf16x8 afh[4], afl[4];
    #pragma unroll
    for (int kt = 0; kt < 4; ++kt) {
        int row = w * 16 + ar, cb = kt * 4 + kg;
        int idx = row * 16 + (cb ^ (row & 7));
        afh[kt] = ((const bf16x8*)Ash)[idx];
        afl[kt] = ((const bf16x8*)Asl)[idx];
    }
    f32x4 acc[4];
    #pragma unroll
    for (int nt = 0; nt < 4; ++nt) { acc[nt][0] = 0.f; acc[nt][1] = 0.f; acc[nt][2] = 0.f; acc[nt][3] = 0.f; }
    #pragma unroll
    for (int nt = 0; nt < 4; ++nt) {
        #pragma unroll
        for (int kt = 0; kt < 4; ++kt) {
            int n = nt * 16 + ar, cb = kt * 4 + kg;
            int idx = n * 16 + (cb ^ (n & 7));
            bf16x8 bfh = ((const bf16x8*)Bsh)[idx];
            bf16x8 bfl = ((const bf16x8*)Bsl)[idx];
            acc[nt] = __builtin_amdgcn_mfma_f32_16x16x32_bf16(afh[kt], bfh, acc[nt], 0, 0, 0);
            acc[nt] = __builtin_amdgcn_mfma_f32_16x16x32_bf16(afl[kt], bfh, acc[nt], 0, 0, 0);
            acc[nt] = __builtin_amdgcn_mfma_f32_16x16x32_bf16(afh[kt], bfl, acc[nt], 0, 0, 0);
        }
    }
    int rb = base + w * 16 + kg * 4;
    #pragma unroll
    for (int nt = 0; nt < 4; ++nt) {
        int colg = ncol0 + nt * 16 + ar;
        float bv = bias[colg];
        float s = 0.f, q = 0.f;
        #pragma unroll
        for (int r = 0; r < 4; ++r) {
            int node = rb + r;
            float d = acc[nt][r] + bv;
            if (node < NN) out[(size_t)node * 128 + colg] = d;
            d = (node < NN) ? d : 0.f;
            s += d; q += d * d;
        }
        s += __shfl_xor(s, 16); s += __shfl_xor(s, 32);
        q += __shfl_xor(q, 16); q += __shfl_xor(q, 32);
        int col = nt * 16 + ar;
        if (kg == 0) { red[w * 128 + col] = s; red[w * 128 + 64 + col] = q; }
    }
    __syncthreads();
    if (t < 128) {
        int c = t & 63, which = t >> 6;
        float v = red[0 * 128 + which * 64 + c] + red[1 * 128 + which * 64 + c]
                + red[2 * 128 + which * 64 + c] + red[3 * 128 + which * 64 + c];
        atomicAdd(&statsOut[which * 128 + ncol0 + c], v);
    }
}

// ---- fused: x = lrelu(bn(h)); aggrOut = (1+eps[nextLayer]) * x
__global__ __launch_bounds__(256) void k_bn2(
    const float* __restrict__ in, const float* __restrict__ stats,
    const float* __restrict__ g, const float* __restrict__ b,
    const float* __restrict__ eps, int nextLayer,
    float* __restrict__ xout, float* __restrict__ aggrOut)
{
    int tid = blockIdx.x * 256 + threadIdx.x;
    float e1 = 1.f + eps[nextLayer];
    for (int i = tid; i < NN * 16; i += gridDim.x * 256) {
        int c4 = (i & 15) << 2;
        float4 v = ((const float4*)in)[i];
        float o[4] = {v.x, v.y, v.z, v.w};
        #pragma unroll
        for (int j = 0; j < 4; ++j) {
            int c = c4 + j;
            float m = stats[c] * (1.f / NN);
            float vv = stats[64 + c] * (1.f / NN) - m * m;
            float s = g[c] * rsqrtf(vv + BN_EPS);
            o[j] = lrelu(fmaf(o[j] - m, s, b[c]));
        }
        float4 r = {o[0], o[1], o[2], o[3]};
        ((float4*)xout)[i] = r;
        float4 r2 = {o[0] * e1, o[1] * e1, o[2] * e1, o[3] * e1};
        ((float4*)aggrOut)[i] = r2;
    }
}

// ---- out[n] = lrelu(bn(h128[n])) . cW3 + cb3
__global__ __launch_bounds__(256) void k_out(
    const float* __restrict__ h, const float* __restrict__ stats,
    const float* __restrict__ g, const float* __restrict__ b,
    const float* __restrict__ W3, const float* __restrict__ b3,
    float* __restrict__ outv)
{
    int lane = threadIdx.x & 63;
    int wid = (blockIdx.x * 256 + threadIdx.x) >> 6;
    int nw = (gridDim.x * 256) >> 6;
    float m0 = stats[lane] * (1.f / NN);
    float v0 = stats[128 + lane] * (1.f / NN) - m0 * m0;
    float s0 = g[lane] * rsqrtf(v0 + BN_EPS);
    float h0 = b[lane] - m0 * s0;
    float m1 = stats[64 + lane] * (1.f / NN);
    float v1 = stats[128 + 64 + lane] * (1.f / NN) - m1 * m1;
    float s1 = g[64 + lane] * rsqrtf(v1 + BN_EPS);
    float h1 = b[64 + lane] - m1 * s1;
    float w0 = W3[lane], w1 = W3[64 + lane];
    float bb = b3[0];
    for (int n = wid; n < NN; n += nw) {
        float a = h[(size_t)n * 128 + lane];
        float c = h[(size_t)n * 128 + 64 + lane];
        a = lrelu(fmaf(a, s0, h0));
        c = lrelu(fmaf(c, s1, h1));
        float p = a * w0 + c * w1;
        p += __shfl_xor(p, 32);
        p += __shfl_xor(p, 16);
        p += __shfl_xor(p, 8);
        p += __shfl_xor(p, 4);
        p += __shfl_xor(p, 2);
        p += __shfl_xor(p, 1);
        if (lane == 0) outv[n] = p + bb;
    }
}

extern "C" void kernel_launch(void* const* d_in, const int* in_sizes, int n_in,
                              void* d_out, int out_size, void* d_ws, size_t ws_size,
                              hipStream_t stream)
{
    const float* x0   = (const float*)d_in[0];
    const float* ea   = (const float*)d_in[1];
    const float* leW  = (const float*)d_in[2];
    const float* leb  = (const float*)d_in[3];
    const float* W1   = (const float*)d_in[4];
    const float* b1   = (const float*)d_in[5];
    const float* g1   = (const float*)d_in[6];
    const float* bb1  = (const float*)d_in[7];
    const float* W2   = (const float*)d_in[8];
    const float* b2   = (const float*)d_in[9];
    const float* eps  = (const float*)d_in[10];
    const float* og   = (const float*)d_in[11];
    const float* ob   = (const float*)d_in[12];
    const float* cW1  = (const float*)d_in[13];
    const float* cb1  = (const float*)d_in[14];
    const float* cg1  = (const float*)d_in[15];
    const float* cbb1 = (const float*)d_in[16];
    const float* cW2  = (const float*)d_in[17];
    const float* cb2  = (const float*)d_in[18];
    const float* cg2  = (const float*)d_in[19];
    const float* cbb2 = (const float*)d_in[20];
    const float* cW3  = (const float*)d_in[21];
    const float* cb3  = (const float*)d_in[22];
    const int* ei     = (const int*)d_in[23];
    const int* batch  = (const int*)d_in[24];
    const int* src = ei;
    const int* dst = ei + NE;

    // ---- workspace layout (4-byte units). perm/sds alias h128 (disjoint lifetimes).
    float* xbuf   = (float*)d_ws;                       // NN*64
    float* hbuf   = xbuf + (size_t)NN * 64;             // NN*64
    float* h128   = hbuf + (size_t)NN * 64;             // NN*128 (head)
    int*   perm   = (int*)h128;                         // NE (layers) — alias
    unsigned* sds = (unsigned*)(perm + NE);             // NE (layers) — alias
    float* pool   = h128 + (size_t)NN * 128;            // NG*64
    float* cstats = pool + (size_t)NG * 64;             // 512
    float* stats  = cstats + 512;                       // 768 (3 x 256)
    int*   cnt    = (int*)(stats + 768);                // NN
    int*   off    = cnt + NN;                           // NN+1 (+pad)
    int*   cur    = off + NN + 4;                       // NN
    int*   bsum   = cur + NN;                           // 256
    int*   boff   = bsum + 256;                         // 256
    unsigned short* w1h  = (unsigned short*)(boff + 256); // 3*4096 each
    unsigned short* w1l  = w1h + 3 * 4096;
    unsigned short* w2h  = w1l + 3 * 4096;
    unsigned short* w2l  = w2h + 3 * 4096;
    unsigned short* cw1h = w2l + 3 * 4096;              // 16384 each
    unsigned short* cw1l = cw1h + 16384;
    unsigned short* cw2h = cw1l + 16384;
    unsigned short* cw2l = cw2h + 16384;
    float* outp   = (float*)d_out;

    int zeroN = NG * 64 + 512 + 768 + NN;  // pool..cnt contiguous

    int fGrid  = (NN + 63) / 64;            // 782 (MFMA GEMMs)
    int aGrid  = (NCHUNK + 31) / 32;        // 1563 (k_aggr_m: 32 chunks/block)

    // ---- one-time: zero, weight cvt, CSR build, perm scatter + sds fill
    k_prep<<<512, 256, 0, stream>>>((int*)pool, zeroN);
    k_wcvt<<<8, 256, 0, stream>>>(W1, W2, cW1, cW2, w1h, w1l, w2h, w2l,
                                  cw1h, cw1l, cw2h, cw2l);
    k_hist<<<1024, 256, 0, stream>>>(dst, cnt);
    k_scanA<<<NB_SCAN, 256, 0, stream>>>(cnt, off, bsum);
    k_scanB<<<1, 256, 0, stream>>>(bsum, boff);
    k_scanC<<<NB_SCAN, 256, 0, stream>>>(cnt, off, boff, cur);
    k_scatterP<<<2048, 256, 0, stream>>>(dst, cur, perm);
    k_sds<<<1024, 256, 0, stream>>>(src, dst, perm, sds);

    k_init<<<1024, 256, 0, stream>>>(x0, eps, 0, hbuf);
    for (int l = 0; l < 3; ++l) {
        const float* xc = (l == 0) ? x0 : xbuf;
        float* st = stats + l * 256;
        k_aggr_m<<<aGrid, 256, 0, stream>>>(xc, ea, perm, sds,
                leW + l * 1024, leb + l * 64, hbuf);
        k_mm64_f<0, 0><<<fGrid, 256, 0, stream>>>(hbuf, w1h + l * 4096, w1l + l * 4096,
                b1 + l * 64, nullptr, nullptr, nullptr, hbuf, st, nullptr, nullptr);
        if (l < 2) {
            k_mm64_f<1, 0><<<fGrid, 256, 0, stream>>>(hbuf, w2h + l * 4096, w2l + l * 4096,
                    b2 + l * 64, st, g1 + l * 64, bb1 + l * 64, hbuf, st + 128,
                    nullptr, nullptr);
            k_bn2<<<1024, 256, 0, stream>>>(hbuf, st + 128, og + l * 64, ob + l * 64,
                    eps, l + 1, xbuf, hbuf);
        } else {
            k_mm64_f<1, 1><<<fGrid, 256, 0, stream>>>(hbuf, w2h + l * 4096, w2l + l * 4096,
                    b2 + l * 64, st, g1 + l * 64, bb1 + l * 64, xbuf, nullptr,
                    batch, pool);
        }
    }
    k_cmm_f<0><<<fGrid * 2, 256, 0, stream>>>(xbuf, pool, batch, nullptr, nullptr, nullptr,
                                              cw1h, cw1l, cb1, h128, cstats);
    k_cmm_f<1><<<fGrid * 2, 256, 0, stream>>>(h128, nullptr, nullptr, cstats, cg1, cbb1,
                                              cw2h, cw2l, cb2, h128, cstats + 256);
    k_out<<<1024, 256, 0, stream>>>(h128, cstats + 256, cg2, cbb2, cW3, cb3, outp);
}

// Round 14
// 588.212 us; speedup vs baseline: 1.0035x; 1.0035x over previous
//
#include <hip/hip_runtime.h>

#define NN 50000
#define NE 800000
#define NG 2000
#define BN_EPS 1e-5f
#define NB_SCAN 196   // ceil(NN/256)
#define NCHUNK 50000  // NE/16

typedef __attribute__((ext_vector_type(8))) short bf16x8;
typedef __attribute__((ext_vector_type(4))) float f32x4;
typedef __attribute__((ext_vector_type(4))) unsigned u32x4;

__device__ __forceinline__ float lrelu(float v) { return v > 0.f ? v : 0.01f * v; }

__device__ __forceinline__ unsigned short f2bf(float x) {
    union { float f; unsigned u; } v; v.f = x;
    unsigned r = v.u + 0x7FFF + ((v.u >> 16) & 1);
    return (unsigned short)(r >> 16);
}
__device__ __forceinline__ float bf2f(unsigned short h) {
    union { unsigned u; float f; } v; v.u = ((unsigned)h) << 16;
    return v.f;
}
__device__ __forceinline__ bf16x8 u4_to_bf(uint4 u) {
    union { uint4 q; bf16x8 b; } c; c.q = u; return c.b;
}

// ---- zero pool+cstats+stats+cnt
__global__ __launch_bounds__(256) void k_prep(int* __restrict__ p, int n)
{
    int tid = blockIdx.x * 256 + threadIdx.x;
    for (int i = tid; i < n; i += gridDim.x * 256) p[i] = 0;
}

// ---- convert + transpose GEMM weights to split bf16 (hi+lo) [N][K]
__global__ __launch_bounds__(256) void k_wcvt(
    const float* __restrict__ W1, const float* __restrict__ W2,
    const float* __restrict__ cW1, const float* __restrict__ cW2,
    unsigned short* __restrict__ w1h, unsigned short* __restrict__ w1l,
    unsigned short* __restrict__ w2h, unsigned short* __restrict__ w2l,
    unsigned short* __restrict__ cw1h, unsigned short* __restrict__ cw1l,
    unsigned short* __restrict__ cw2h, unsigned short* __restrict__ cw2l)
{
    int b = blockIdx.x, t = threadIdx.x;
    if (b < 6) {
        const float* s = (b < 3) ? (W1 + b * 4096) : (W2 + (b - 3) * 4096);
        unsigned short* dh = (b < 3) ? (w1h + b * 4096) : (w2h + (b - 3) * 4096);
        unsigned short* dl = (b < 3) ? (w1l + b * 4096) : (w2l + (b - 3) * 4096);
        for (int i = t; i < 4096; i += 256) {
            int k = i >> 6, n = i & 63;
            float v = s[i];
            unsigned short h = f2bf(v);
            dh[n * 64 + k] = h;
            dl[n * 64 + k] = f2bf(v - bf2f(h));
        }
    } else {
        const float* s = (b == 6) ? cW1 : cW2;
        unsigned short* dh = (b == 6) ? cw1h : cw2h;
        unsigned short* dl = (b == 6) ? cw1l : cw2l;
        for (int i = t; i < 16384; i += 256) {
            int k = i >> 7, n = i & 127;
            float v = s[i];
            unsigned short h = f2bf(v);
            dh[n * 128 + k] = h;
            dl[n * 128 + k] = f2bf(v - bf2f(h));
        }
    }
}

// ---- histogram of dst
__global__ __launch_bounds__(256) void k_hist(const int* __restrict__ dst, int* __restrict__ cnt)
{
    int tid = blockIdx.x * 256 + threadIdx.x;
    for (int e = tid; e < NE; e += gridDim.x * 256) atomicAdd(&cnt[dst[e]], 1);
}

__global__ __launch_bounds__(256) void k_scanA(const int* __restrict__ cnt,
    int* __restrict__ off, int* __restrict__ bsum)
{
    __shared__ int s[256];
    int t = threadIdx.x;
    int i = blockIdx.x * 256 + t;
    int v = (i < NN) ? cnt[i] : 0;
    s[t] = v; __syncthreads();
    #pragma unroll
    for (int d = 1; d < 256; d <<= 1) {
        int u = (t >= d) ? s[t - d] : 0;
        __syncthreads();
        s[t] += u;
        __syncthreads();
    }
    if (i < NN) off[i + 1] = s[t];
    if (t == 255) bsum[blockIdx.x] = s[255];
}

__global__ __launch_bounds__(256) void k_scanB(const int* __restrict__ bsum, int* __restrict__ boff)
{
    __shared__ int s[256];
    int t = threadIdx.x;
    int v = (t < NB_SCAN) ? bsum[t] : 0;
    s[t] = v; __syncthreads();
    #pragma unroll
    for (int d = 1; d < 256; d <<= 1) {
        int u = (t >= d) ? s[t - d] : 0;
        __syncthreads();
        s[t] += u;
        __syncthreads();
    }
    boff[t] = s[t] - v;
}

__global__ __launch_bounds__(256) void k_scanC(const int* __restrict__ cnt,
    int* __restrict__ off, const int* __restrict__ boff, int* __restrict__ cur)
{
    int i = blockIdx.x * 256 + threadIdx.x;
    if (i < NN) {
        int incl = off[i + 1] + boff[blockIdx.x];
        off[i + 1] = incl;
        cur[i] = incl - cnt[i];
    }
    if (i == 0) off[0] = 0;
}

// ---- fused scatter + edge-attr convert: ONE 64B record per edge:
// [16 bf16 hi | 12 bf16 lo | src int | dst int] — non-temporal full-line store
__global__ __launch_bounds__(256) void k_scatter2(
    const int* __restrict__ src, const int* __restrict__ dst,
    int* __restrict__ cur, const float* __restrict__ ea,
    unsigned short* __restrict__ eaz)
{
    int tid = blockIdx.x * 256 + threadIdx.x;
    for (int e = tid; e < NE; e += gridDim.x * 256) {
        int s = src[e], d = dst[e];
        int p = atomicAdd(&cur[d], 1);
        const f32x4* ap = (const f32x4*)(ea + (size_t)e * 16);
        f32x4 a0 = __builtin_nontemporal_load(ap);
        f32x4 a1 = __builtin_nontemporal_load(ap + 1);
        f32x4 a2 = __builtin_nontemporal_load(ap + 2);
        f32x4 a3 = __builtin_nontemporal_load(ap + 3);
        float v[16] = {a0[0], a0[1], a0[2], a0[3], a1[0], a1[1], a1[2], a1[3],
                       a2[0], a2[1], a2[2], a2[3], a3[0], a3[1], a3[2], a3[3]};
        unsigned hi[8], lo[6];
        #pragma unroll
        for (int j = 0; j < 8; ++j) {
            unsigned short h0 = f2bf(v[2 * j]), h1 = f2bf(v[2 * j + 1]);
            hi[j] = (unsigned)h0 | ((unsigned)h1 << 16);
            if (j < 6)
                lo[j] = (unsigned)f2bf(v[2 * j] - bf2f(h0))
                      | ((unsigned)f2bf(v[2 * j + 1] - bf2f(h1)) << 16);
        }
        u32x4* rec = (u32x4*)(eaz + (size_t)p * 32);
        u32x4 r0 = {hi[0], hi[1], hi[2], hi[3]};
        u32x4 r1 = {hi[4], hi[5], hi[6], hi[7]};
        u32x4 r2 = {lo[0], lo[1], lo[2], lo[3]};
        u32x4 r3 = {lo[4], lo[5], (unsigned)s, (unsigned)d};
        __builtin_nontemporal_store(r0, rec);
        __builtin_nontemporal_store(r1, rec + 1);
        __builtin_nontemporal_store(r2, rec + 2);
        __builtin_nontemporal_store(r3, rec + 3);
    }
}

// ---- aggr = (1+eps[l]) * x  (layer 0 only; later layers fused into k_bn2)
__global__ __launch_bounds__(256) void k_init(const float* __restrict__ x,
    const float* __restrict__ eps, int layer, float* __restrict__ aggr)
{
    int tid = blockIdx.x * 256 + threadIdx.x;
    float s = 1.f + eps[layer];
    const float4* xv = (const float4*)x;
    float4* av = (float4*)aggr;
    for (int i = tid; i < NN * 16; i += gridDim.x * 256) {
        float4 v = xv[i];
        v.x *= s; v.y *= s; v.z *= s; v.w *= s;
        av[i] = v;
    }
}

// ---- MFMA edge aggregation: wave owns 8 chunks x 16 sorted edges.
__global__ __launch_bounds__(256) void k_aggr_m(
    const float* __restrict__ x, const unsigned short* __restrict__ eaz,
    const float* __restrict__ We, const float* __restrict__ be,
    float* __restrict__ aggr)
{
    __shared__ unsigned short wth[1024], wtl[1024];  // [col][k] transposed We hi/lo
    __shared__ float els[4 * 16 * 65];               // per-wave e' tile [16 edges][65]
    int t = threadIdx.x;
    for (int i = t; i < 1024; i += 256) {
        int col = i >> 4, k = i & 15;
        float v = We[k * 64 + col];
        unsigned short h = f2bf(v);
        wth[col * 16 + k] = h;
        wtl[col * 16 + k] = f2bf(v - bf2f(h));
    }
    __syncthreads();

    int lane = t & 63, w = t >> 6;
    float* myels = els + w * (16 * 65);
    int ar = lane & 15;
    int kg = (lane >> 4) & 1;
    bool klive = lane < 32;

    bf16x8 bh[4], bl[4];
    float bias4[4];
    #pragma unroll
    for (int nc = 0; nc < 4; ++nc) {
        int col = nc * 16 + ar;
        uint4 hv = {0, 0, 0, 0}, lv = {0, 0, 0, 0};
        if (klive) {
            hv = *(const uint4*)(wth + col * 16 + kg * 8);
            lv = *(const uint4*)(wtl + col * 16 + kg * 8);
        }
        bh[nc] = u4_to_bf(hv);
        bl[nc] = u4_to_bf(lv);
        bias4[nc] = be[col];
    }

    int cbase0 = (blockIdx.x * 4 + w) * 8;
    for (int ci = 0; ci < 8; ++ci) {
        int chunk = cbase0 + ci;
        if (chunk >= NCHUNK) break;
        int e0 = chunk * 16;
        const unsigned short* rec = eaz + (size_t)(e0 + ar) * 32;

        // src/dst live in the record tail (same 64B line as fragments)
        int2 sdv = *(const int2*)(rec + 28);
        int sl = sdv.x, dl = sdv.y;

        uint4 hv = {0, 0, 0, 0}, lv = {0, 0, 0, 0};
        if (klive) {
            hv = *(const uint4*)(rec + kg * 8);
            lv = *(const uint4*)(rec + 16 + kg * 8);
            if (kg) { lv.z = 0; lv.w = 0; }  // tail words hold src/dst, not lo
        }
        bf16x8 ah = u4_to_bf(hv), al = u4_to_bf(lv);

        float xv[16];
        #pragma unroll
        for (int e = 0; e < 16; ++e) {
            int s_e = __builtin_amdgcn_readlane(sl, e);
            xv[e] = x[(size_t)s_e * 64 + lane];
        }

        #pragma unroll
        for (int nc = 0; nc < 4; ++nc) {
            f32x4 acc;
            acc[0] = bias4[nc]; acc[1] = bias4[nc]; acc[2] = bias4[nc]; acc[3] = bias4[nc];
            acc = __builtin_amdgcn_mfma_f32_16x16x32_bf16(ah, bh[nc], acc, 0, 0, 0);
            acc = __builtin_amdgcn_mfma_f32_16x16x32_bf16(al, bh[nc], acc, 0, 0, 0);
            acc = __builtin_amdgcn_mfma_f32_16x16x32_bf16(ah, bl[nc], acc, 0, 0, 0);
            int rbase = (lane >> 4) * 4;
            #pragma unroll
            for (int r = 0; r < 4; ++r)
                myels[(rbase + r) * 65 + nc * 16 + ar] = acc[r];
        }

        int d = __builtin_amdgcn_readlane(dl, 0);
        float acc = 0.f;
        #pragma unroll
        for (int e = 0; e < 16; ++e) {
            float m = xv[e] + myels[e * 65 + lane];
            m = fmaxf(m, 0.f);
            acc += m;
            int dn = (e < 15) ? __builtin_amdgcn_readlane(dl, e + 1) : -1;
            if (dn != d) {
                atomicAdd(&aggr[(size_t)d * 64 + lane], acc);
                acc = 0.f;
                d = dn;
            }
        }
    }
}

// ---- split-bf16 MFMA [N,64]@Wt+b. PRE: BN+lrelu input. POST0: raw+stats. POST1: lrelu (+pool).
template<int PRE, int POST>
__global__ __launch_bounds__(256) void k_mm64_f(
    const float* __restrict__ in,
    const unsigned short* __restrict__ Wh, const unsigned short* __restrict__ Wl,
    const float* __restrict__ bias, const float* __restrict__ statsIn,
    const float* __restrict__ gIn, const float* __restrict__ bIn,
    float* __restrict__ out, float* __restrict__ statsOut,
    const int* __restrict__ batch, float* __restrict__ pool)
{
    __shared__ unsigned short Ash[64 * 64], Asl[64 * 64];
    __shared__ unsigned short Bsh[64 * 64], Bsl[64 * 64];
    __shared__ float sc[64], sh[64];
    __shared__ float red[4 * 128];
    int t = threadIdx.x;
    int base = blockIdx.x * 64;
    if (PRE && t < 64) {
        float m = statsIn[t] * (1.f / NN);
        float v = statsIn[64 + t] * (1.f / NN) - m * m;
        float s = gIn[t] * rsqrtf(v + BN_EPS);
        sc[t] = s; sh[t] = bIn[t] - m * s;
    }
    for (int i = t; i < 512; i += 256) {
        int n = i >> 3, cb = i & 7;
        ((uint4*)Bsh)[n * 8 + (cb ^ (n & 7))] = ((const uint4*)Wh)[i];
        ((uint4*)Bsl)[n * 8 + (cb ^ (n & 7))] = ((const uint4*)Wl)[i];
    }
    __syncthreads();
    for (int i = t; i < 512; i += 256) {
        int row = i >> 3, cb = i & 7;
        int node = base + row;
        float v[8] = {0.f, 0.f, 0.f, 0.f, 0.f, 0.f, 0.f, 0.f};
        if (node < NN) {
            float4 u0 = *(const float4*)(in + (size_t)node * 64 + cb * 8);
            float4 u1 = *(const float4*)(in + (size_t)node * 64 + cb * 8 + 4);
            v[0] = u0.x; v[1] = u0.y; v[2] = u0.z; v[3] = u0.w;
            v[4] = u1.x; v[5] = u1.y; v[6] = u1.z; v[7] = u1.w;
            if (PRE) {
                #pragma unroll
                for (int j = 0; j < 8; ++j) {
                    int c = cb * 8 + j;
                    v[j] = lrelu(fmaf(v[j], sc[c], sh[c]));
                }
            }
        }
        unsigned hw[4], lw[4];
        #pragma unroll
        for (int j = 0; j < 4; ++j) {
            unsigned short h0 = f2bf(v[2 * j]), h1 = f2bf(v[2 * j + 1]);
            unsigned short l0 = f2bf(v[2 * j] - bf2f(h0)), l1 = f2bf(v[2 * j + 1] - bf2f(h1));
            hw[j] = (unsigned)h0 | ((unsigned)h1 << 16);
            lw[j] = (unsigned)l0 | ((unsigned)l1 << 16);
        }
        uint4 rh = { hw[0], hw[1], hw[2], hw[3] };
        uint4 rl = { lw[0], lw[1], lw[2], lw[3] };
        int idx = row * 8 + (cb ^ (row & 7));
        ((uint4*)Ash)[idx] = rh;
        ((uint4*)Asl)[idx] = rl;
    }
    __syncthreads();

    int w = t >> 6, l = t & 63;
    int ar = l & 15, kg = l >> 4;
    bf16x8 afh[2], afl[2];
    #pragma unroll
    for (int kt = 0; kt < 2; ++kt) {
        int row = w * 16 + ar, cb = kt * 4 + kg;
        int idx = row * 8 + (cb ^ (row & 7));
        afh[kt] = ((const bf16x8*)Ash)[idx];
        afl[kt] = ((const bf16x8*)Asl)[idx];
    }
    f32x4 acc[4];
    #pragma unroll
    for (int nt = 0; nt < 4; ++nt) { acc[nt][0] = 0.f; acc[nt][1] = 0.f; acc[nt][2] = 0.f; acc[nt][3] = 0.f; }
    #pragma unroll
    for (int nt = 0; nt < 4; ++nt) {
        #pragma unroll
        for (int kt = 0; kt < 2; ++kt) {
            int n = nt * 16 + ar, cb = kt * 4 + kg;
            int idx = n * 8 + (cb ^ (n & 7));
            bf16x8 bfh = ((const bf16x8*)Bsh)[idx];
            bf16x8 bfl = ((const bf16x8*)Bsl)[idx];
            acc[nt] = __builtin_amdgcn_mfma_f32_16x16x32_bf16(afh[kt], bfh, acc[nt], 0, 0, 0);
            acc[nt] = __builtin_amdgcn_mfma_f32_16x16x32_bf16(afl[kt], bfh, acc[nt], 0, 0, 0);
            acc[nt] = __builtin_amdgcn_mfma_f32_16x16x32_bf16(afh[kt], bfl, acc[nt], 0, 0, 0);
        }
    }
    int rb = base + w * 16 + kg * 4;
    int bidx[4];
    if (POST == 1) {
        #pragma unroll
        for (int r = 0; r < 4; ++r)
            bidx[r] = (rb + r < NN) ? batch[rb + r] : 0;
    }
    #pragma unroll
    for (int nt = 0; nt < 4; ++nt) {
        int col = nt * 16 + ar;
        float bv = bias[col];
        float s = 0.f, q = 0.f;
        #pragma unroll
        for (int r = 0; r < 4; ++r) {
            int node = rb + r;
            float d = acc[nt][r] + bv;
            if (POST == 1) d = lrelu(d);
            if (node < NN) {
                out[(size_t)node * 64 + col] = d;
                if (POST == 1)
                    atomicAdd(&pool[(size_t)bidx[r] * 64 + col], d);
            }
            if (POST == 0) {
                d = (node < NN) ? d : 0.f;
                s += d; q += d * d;
            }
        }
        if (POST == 0) {
            s += __shfl_xor(s, 16); s += __shfl_xor(s, 32);
            q += __shfl_xor(q, 16); q += __shfl_xor(q, 32);
            if (kg == 0) { red[w * 128 + col] = s; red[w * 128 + 64 + col] = q; }
        }
    }
    if (POST == 0) {
        __syncthreads();
        if (t < 128) {
            int c = t & 63, which = t >> 6;
            float v = red[0 * 128 + which * 64 + c] + red[1 * 128 + which * 64 + c]
                    + red[2 * 128 + which * 64 + c] + red[3 * 128 + which * 64 + c];
            atomicAdd(&statsOut[which * 64 + c], v);
        }
    }
}

// ---- split-bf16 MFMA [N,128]@Wt+b, 64-col blocks.
template<int MODE>
__global__ __launch_bounds__(256) void k_cmm_f(
    const float* __restrict__ inA, const float* __restrict__ pool,
    const int* __restrict__ batch, const float* __restrict__ statsIn,
    const float* __restrict__ gIn, const float* __restrict__ bIn,
    const unsigned short* __restrict__ Wh, const unsigned short* __restrict__ Wl,
    const float* __restrict__ bias,
    float* __restrict__ out, float* __restrict__ statsOut)
{
    __shared__ unsigned short Ash[64 * 128], Asl[64 * 128];
    __shared__ unsigned short Bsh[64 * 128], Bsl[64 * 128];
    __shared__ float sc[128], sh[128];
    __shared__ float red[4 * 128];
    int t = threadIdx.x;
    int base = (blockIdx.x >> 1) * 64;
    int ncol0 = (blockIdx.x & 1) * 64;
    if (MODE == 1 && t < 128) {
        float m = statsIn[t] * (1.f / NN);
        float v = statsIn[128 + t] * (1.f / NN) - m * m;
        float s = gIn[t] * rsqrtf(v + BN_EPS);
        sc[t] = s; sh[t] = bIn[t] - m * s;
    }
    for (int i = t; i < 1024; i += 256) {
        int n = i >> 4, cb = i & 15;
        int idx = n * 16 + (cb ^ (n & 7));
        ((uint4*)Bsh)[idx] = ((const uint4*)Wh)[(ncol0 + n) * 16 + cb];
        ((uint4*)Bsl)[idx] = ((const uint4*)Wl)[(ncol0 + n) * 16 + cb];
    }
    __syncthreads();
    for (int i = t; i < 1024; i += 256) {
        int row = i >> 4, cb = i & 15;
        int node = base + row;
        float v[8] = {0.f, 0.f, 0.f, 0.f, 0.f, 0.f, 0.f, 0.f};
        if (node < NN) {
            const float* sp;
            if (MODE == 0) {
                sp = (cb < 8) ? (inA + (size_t)node * 64 + cb * 8)
                              : (pool + (size_t)batch[node] * 64 + (cb - 8) * 8);
            } else {
                sp = inA + (size_t)node * 128 + cb * 8;
            }
            float4 u0 = *(const float4*)sp;
            float4 u1 = *(const float4*)(sp + 4);
            v[0] = u0.x; v[1] = u0.y; v[2] = u0.z; v[3] = u0.w;
            v[4] = u1.x; v[5] = u1.y; v[6] = u1.z; v[7] = u1.w;
            if (MODE == 1) {
                #pragma unroll
                for (int j = 0; j < 8; ++j) {
                    int c = cb * 8 + j;
                    v[j] = lrelu(fmaf(v[j], sc[c], sh[c]));
                }
            }
        }
        unsigned hw[4], lw[4];
        #pragma unroll
        for (int j = 0; j < 4; ++j) {
            unsigned short h0 = f2bf(v[2 * j]), h1 = f2bf(v[2 * j + 1]);
            unsigned short l0 = f2bf(v[2 * j] - bf2f(h0)), l1 = f2bf(v[2 * j + 1] - bf2f(h1));
            hw[j] = (unsigned)h0 | ((unsigned)h1 << 16);
            lw[j] = (unsigned)l0 | ((unsigned)l1 << 16);
        }
        uint4 rh = { hw[0], hw[1], hw[2], hw[3] };
        uint4 rl = { lw[0], lw[1], lw[2], lw[3] };
        int idx = row * 16 + (cb ^ (row & 7));
        ((uint4*)Ash)[idx] = rh;
        ((uint4*)Asl)[idx] = rl;
    }
    __syncthreads();

    int w = t >> 6, l = t & 63;
    int ar = l & 15, kg = l >> 4;
    bf16x8 afh[4], afl[4];
    #pragma unroll
    for (int kt = 0; kt < 4; ++kt) {
        int row = w * 16 + ar, cb = kt * 4 + kg;
        int idx = row * 16 + (cb ^ (row & 7));
        afh[kt] = ((const bf16x8*)Ash)[idx];
        afl[kt] = ((const bf16x8*)Asl)[idx];
    }
    f32x4 acc[4];
    #pragma unroll
    for (int nt = 0; nt < 4; ++nt) { acc[nt][0] = 0.f; acc[nt][1] = 0.f; acc[nt][2] = 0.f; acc[nt][3] = 0.f; }
    #pragma unroll
    for (int nt = 0; nt < 4; ++nt) {
        #pragma unroll
        for (int kt = 0; kt < 4; ++kt) {
            int n = nt * 16 + ar, cb = kt * 4 + kg;
            int idx = n * 16 + (cb ^ (n & 7));
            bf16x8 bfh = ((const bf16x8*)Bsh)[idx];
            bf16x8 bfl = ((const bf16x8*)Bsl)[idx];
            acc[nt] = __builtin_amdgcn_mfma_f32_16x16x32_bf16(afh[kt], bfh, acc[nt], 0, 0, 0);
            acc[nt] = __builtin_amdgcn_mfma_f32_16x16x32_bf16(afl[kt], bfh, acc[nt], 0, 0, 0);
            acc[nt] = __builtin_amdgcn_mfma_f32_16x16x32_bf16(afh[kt], bfl, acc[nt], 0, 0, 0);
        }
    }
    int rb = base + w * 16 + kg * 4;
    #pragma unroll
    for (int nt = 0; nt < 4; ++nt) {
        int colg = ncol0 + nt * 16 + ar;
        float bv = bias[colg];
        float s = 0.f, q = 0.f;
        #pragma unroll
        for (int r = 0; r < 4; ++r) {
            int node = rb + r;
            float d = acc[nt][r] + bv;
            if (node < NN) out[(size_t)node * 128 + colg] = d;
            d = (node < NN) ? d : 0.f;
            s += d; q += d * d;
        }
        s += __shfl_xor(s, 16); s += __shfl_xor(s, 32);
        q += __shfl_xor(q, 16); q += __shfl_xor(q, 32);
        int col = nt * 16 + ar;
        if (kg == 0) { red[w * 128 + col] = s; red[w * 128 + 64 + col] = q; }
    }
    __syncthreads();
    if (t < 128) {
        int c = t & 63, which = t >> 6;
        float v = red[0 * 128 + which * 64 + c] + red[1 * 128 + which * 64 + c]
                + red[2 * 128 + which * 64 + c] + red[3 * 128 + which * 64 + c];
        atomicAdd(&statsOut[which * 128 + ncol0 + c], v);
    }
}

// ---- fused: x = lrelu(bn(h)); aggrOut = (1+eps[nextLayer]) * x
__global__ __launch_bounds__(256) void k_bn2(
    const float* __restrict__ in, const float* __restrict__ stats,
    const float* __restrict__ g, const float* __restrict__ b,
    const float* __restrict__ eps, int nextLayer,
    float* __restrict__ xout, float* __restrict__ aggrOut)
{
    int tid = blockIdx.x * 256 + threadIdx.x;
    float e1 = 1.f + eps[nextLayer];
    for (int i = tid; i < NN * 16; i += gridDim.x * 256) {
        int c4 = (i & 15) << 2;
        float4 v = ((const float4*)in)[i];
        float o[4] = {v.x, v.y, v.z, v.w};
        #pragma unroll
        for (int j = 0; j < 4; ++j) {
            int c = c4 + j;
            float m = stats[c] * (1.f / NN);
            float vv = stats[64 + c] * (1.f / NN) - m * m;
            float s = g[c] * rsqrtf(vv + BN_EPS);
            o[j] = lrelu(fmaf(o[j] - m, s, b[c]));
        }
        float4 r = {o[0], o[1], o[2], o[3]};
        ((float4*)xout)[i] = r;
        float4 r2 = {o[0] * e1, o[1] * e1, o[2] * e1, o[3] * e1};
        ((float4*)aggrOut)[i] = r2;
    }
}

// ---- out[n] = lrelu(bn(h128[n])) . cW3 + cb3
__global__ __launch_bounds__(256) void k_out(
    const float* __restrict__ h, const float* __restrict__ stats,
    const float* __restrict__ g, const float* __restrict__ b,
    const float* __restrict__ W3, const float* __restrict__ b3,
    float* __restrict__ outv)
{
    int lane = threadIdx.x & 63;
    int wid = (blockIdx.x * 256 + threadIdx.x) >> 6;
    int nw = (gridDim.x * 256) >> 6;
    float m0 = stats[lane] * (1.f / NN);
    float v0 = stats[128 + lane] * (1.f / NN) - m0 * m0;
    float s0 = g[lane] * rsqrtf(v0 + BN_EPS);
    float h0 = b[lane] - m0 * s0;
    float m1 = stats[64 + lane] * (1.f / NN);
    float v1 = stats[128 + 64 + lane] * (1.f / NN) - m1 * m1;
    float s1 = g[64 + lane] * rsqrtf(v1 + BN_EPS);
    float h1 = b[64 + lane] - m1 * s1;
    float w0 = W3[lane], w1 = W3[64 + lane];
    float bb = b3[0];
    for (int n = wid; n < NN; n += nw) {
        float a = h[(size_t)n * 128 + lane];
        float c = h[(size_t)n * 128 + 64 + lane];
        a = lrelu(fmaf(a, s0, h0));
        c = lrelu(fmaf(c, s1, h1));
        float p = a * w0 + c * w1;
        p += __shfl_xor(p, 32);
        p += __shfl_xor(p, 16);
        p += __shfl_xor(p, 8);
        p += __shfl_xor(p, 4);
        p += __shfl_xor(p, 2);
        p += __shfl_xor(p, 1);
        if (lane == 0) outv[n] = p + bb;
    }
}

extern "C" void kernel_launch(void* const* d_in, const int* in_sizes, int n_in,
                              void* d_out, int out_size, void* d_ws, size_t ws_size,
                              hipStream_t stream)
{
    const float* x0   = (const float*)d_in[0];
    const float* ea   = (const float*)d_in[1];
    const float* leW  = (const float*)d_in[2];
    const float* leb  = (const float*)d_in[3];
    const float* W1   = (const float*)d_in[4];
    const float* b1   = (const float*)d_in[5];
    const float* g1   = (const float*)d_in[6];
    const float* bb1  = (const float*)d_in[7];
    const float* W2   = (const float*)d_in[8];
    const float* b2   = (const float*)d_in[9];
    const float* eps  = (const float*)d_in[10];
    const float* og   = (const float*)d_in[11];
    const float* ob   = (const float*)d_in[12];
    const float* cW1  = (const float*)d_in[13];
    const float* cb1  = (const float*)d_in[14];
    const float* cg1  = (const float*)d_in[15];
    const float* cbb1 = (const float*)d_in[16];
    const float* cW2  = (const float*)d_in[17];
    const float* cb2  = (const float*)d_in[18];
    const float* cg2  = (const float*)d_in[19];
    const float* cbb2 = (const float*)d_in[20];
    const float* cW3  = (const float*)d_in[21];
    const float* cb3  = (const float*)d_in[22];
    const int* ei     = (const int*)d_in[23];
    const int* batch  = (const int*)d_in[24];
    const int* src = ei;
    const int* dst = ei + NE;

    // ---- workspace layout (4-byte units). eaz aliases h128 (disjoint lifetimes).
    float* xbuf   = (float*)d_ws;                       // NN*64
    float* hbuf   = xbuf + (size_t)NN * 64;             // NN*64
    unsigned short* eaz = (unsigned short*)(hbuf + (size_t)NN * 64); // NE*32 ushort (64B/edge)
    float* h128   = (float*)eaz;                        // NN*128 (head) — alias
    float* pool   = (float*)(eaz + (size_t)NE * 32);    // NG*64
    float* cstats = pool + (size_t)NG * 64;             // 512
    float* stats  = cstats + 512;                       // 768 (3 x 256)
    int*   cnt    = (int*)(stats + 768);                // NN
    int*   off    = cnt + NN;                           // NN+1 (+pad)
    int*   cur    = off + NN + 4;                       // NN
    int*   bsum   = cur + NN;                           // 256
    int*   boff   = bsum + 256;                         // 256
    unsigned short* w1h  = (unsigned short*)(boff + 256); // 3*4096 each
    unsigned short* w1l  = w1h + 3 * 4096;
    unsigned short* w2h  = w1l + 3 * 4096;
    unsigned short* w2l  = w2h + 3 * 4096;
    unsigned short* cw1h = w2l + 3 * 4096;              // 16384 each
    unsigned short* cw1l = cw1h + 16384;
    unsigned short* cw2h = cw1l + 16384;
    unsigned short* cw2l = cw2h + 16384;
    float* outp   = (float*)d_out;

    int zeroN = NG * 64 + 512 + 768 + NN;  // pool..cnt contiguous

    int fGrid  = (NN + 63) / 64;            // 782 (MFMA GEMMs)
    int aGrid  = (NCHUNK + 31) / 32;        // 1563 (k_aggr_m: 32 chunks/block)

    // ---- one-time: zero, weight cvt, CSR build, fused scatter+convert
    k_prep<<<512, 256, 0, stream>>>((int*)pool, zeroN);
    k_wcvt<<<8, 256, 0, stream>>>(W1, W2, cW1, cW2, w1h, w1l, w2h, w2l,
                                  cw1h, cw1l, cw2h, cw2l);
    k_hist<<<1024, 256, 0, stream>>>(dst, cnt);
    k_scanA<<<NB_SCAN, 256, 0, stream>>>(cnt, off, bsum);
    k_scanB<<<1, 256, 0, stream>>>(bsum, boff);
    k_scanC<<<NB_SCAN, 256, 0, stream>>>(cnt, off, boff, cur);
    k_scatter2<<<2048, 256, 0, stream>>>(src, dst, cur, ea, eaz);

    k_init<<<1024, 256, 0, stream>>>(x0, eps, 0, hbuf);
    for (int l = 0; l < 3; ++l) {
        const float* xc = (l == 0) ? x0 : xbuf;
        float* st = stats + l * 256;
        k_aggr_m<<<aGrid, 256, 0, stream>>>(xc, eaz,
                leW + l * 1024, leb + l * 64, hbuf);
        k_mm64_f<0, 0><<<fGrid, 256, 0, stream>>>(hbuf, w1h + l * 4096, w1l + l * 4096,
                b1 + l * 64, nullptr, nullptr, nullptr, hbuf, st, nullptr, nullptr);
        if (l < 2) {
            k_mm64_f<1, 0><<<fGrid, 256, 0, stream>>>(hbuf, w2h + l * 4096, w2l + l * 4096,
                    b2 + l * 64, st, g1 + l * 64, bb1 + l * 64, hbuf, st + 128,
                    nullptr, nullptr);
            k_bn2<<<1024, 256, 0, stream>>>(hbuf, st + 128, og + l * 64, ob + l * 64,
                    eps, l + 1, xbuf, hbuf);
        } else {
            k_mm64_f<1, 1><<<fGrid, 256, 0, stream>>>(hbuf, w2h + l * 4096, w2l + l * 4096,
                    b2 + l * 64, st, g1 + l * 64, bb1 + l * 64, xbuf, nullptr,
                    batch, pool);
        }
    }
    k_cmm_f<0><<<fGrid * 2, 256, 0, stream>>>(xbuf, pool, batch, nullptr, nullptr, nullptr,
                                              cw1h, cw1l, cb1, h128, cstats);
    k_cmm_f<1><<<fGrid * 2, 256, 0, stream>>>(h128, nullptr, nullptr, cstats, cg1, cbb1,
                                              cw2h, cw2l, cb2, h128, cstats + 256);
    k_out<<<1024, 256, 0, stream>>>(h128, cstats + 256, cg2, cbb2, cW3, cb3, outp);
}

// Round 16
// 537.154 us; speedup vs baseline: 1.0988x; 1.0951x over previous
//
#include <hip/hip_runtime.h>

#define NN 50000
#define NE 800000
#define NG 2000
#define BN_EPS 1e-5f
#define NB_SCAN 196   // ceil(NN/256)
#define NCHUNK 50000  // NE/16

typedef __attribute__((ext_vector_type(8))) short bf16x8;
typedef __attribute__((ext_vector_type(4))) float f32x4;

__device__ __forceinline__ float lrelu(float v) { return v > 0.f ? v : 0.01f * v; }

__device__ __forceinline__ unsigned short f2bf(float x) {
    union { float f; unsigned u; } v; v.f = x;
    unsigned r = v.u + 0x7FFF + ((v.u >> 16) & 1);
    return (unsigned short)(r >> 16);
}
__device__ __forceinline__ float bf2f(unsigned short h) {
    union { unsigned u; float f; } v; v.u = ((unsigned)h) << 16;
    return v.f;
}
__device__ __forceinline__ bf16x8 u4_to_bf(uint4 u) {
    union { uint4 q; bf16x8 b; } c; c.q = u; return c.b;
}

// ---- merged one-time setup: zero regions + weight convert (disjoint data, safe)
// blocks [0,512): zero; [512,520): wcvt
__global__ __launch_bounds__(256) void k_setup(
    int* __restrict__ zp, int zn,
    const float* __restrict__ W1, const float* __restrict__ W2,
    const float* __restrict__ cW1, const float* __restrict__ cW2,
    unsigned short* __restrict__ w1h, unsigned short* __restrict__ w1l,
    unsigned short* __restrict__ w2h, unsigned short* __restrict__ w2l,
    unsigned short* __restrict__ cw1h, unsigned short* __restrict__ cw1l,
    unsigned short* __restrict__ cw2h, unsigned short* __restrict__ cw2l)
{
    int t = threadIdx.x;
    if (blockIdx.x < 512) {
        int tid = blockIdx.x * 256 + t;
        for (int i = tid; i < zn; i += 512 * 256) zp[i] = 0;
    } else {
        int b = blockIdx.x - 512;
        if (b < 6) {
            const float* s = (b < 3) ? (W1 + b * 4096) : (W2 + (b - 3) * 4096);
            unsigned short* dh = (b < 3) ? (w1h + b * 4096) : (w2h + (b - 3) * 4096);
            unsigned short* dl = (b < 3) ? (w1l + b * 4096) : (w2l + (b - 3) * 4096);
            for (int i = t; i < 4096; i += 256) {
                int k = i >> 6, n = i & 63;
                float v = s[i];
                unsigned short h = f2bf(v);
                dh[n * 64 + k] = h;
                dl[n * 64 + k] = f2bf(v - bf2f(h));
            }
        } else {
            const float* s = (b == 6) ? cW1 : cW2;
            unsigned short* dh = (b == 6) ? cw1h : cw2h;
            unsigned short* dl = (b == 6) ? cw1l : cw2l;
            for (int i = t; i < 16384; i += 256) {
                int k = i >> 7, n = i & 127;
                float v = s[i];
                unsigned short h = f2bf(v);
                dh[n * 128 + k] = h;
                dl[n * 128 + k] = f2bf(v - bf2f(h));
            }
        }
    }
}

// ---- histogram of dst (must run AFTER cnt is zeroed — separate launch)
__global__ __launch_bounds__(256) void k_hist(const int* __restrict__ dst, int* __restrict__ cnt)
{
    int tid = blockIdx.x * 256 + threadIdx.x;
    for (int e = tid; e < NE; e += gridDim.x * 256) atomicAdd(&cnt[dst[e]], 1);
}

__global__ __launch_bounds__(256) void k_scanA(const int* __restrict__ cnt,
    int* __restrict__ off, int* __restrict__ bsum)
{
    __shared__ int s[256];
    int t = threadIdx.x;
    int i = blockIdx.x * 256 + t;
    int v = (i < NN) ? cnt[i] : 0;
    s[t] = v; __syncthreads();
    #pragma unroll
    for (int d = 1; d < 256; d <<= 1) {
        int u = (t >= d) ? s[t - d] : 0;
        __syncthreads();
        s[t] += u;
        __syncthreads();
    }
    if (i < NN) off[i + 1] = s[t];
    if (t == 255) bsum[blockIdx.x] = s[255];
}

__global__ __launch_bounds__(256) void k_scanB(const int* __restrict__ bsum, int* __restrict__ boff)
{
    __shared__ int s[256];
    int t = threadIdx.x;
    int v = (t < NB_SCAN) ? bsum[t] : 0;
    s[t] = v; __syncthreads();
    #pragma unroll
    for (int d = 1; d < 256; d <<= 1) {
        int u = (t >= d) ? s[t - d] : 0;
        __syncthreads();
        s[t] += u;
        __syncthreads();
    }
    boff[t] = s[t] - v;
}

__global__ __launch_bounds__(256) void k_scanC(const int* __restrict__ cnt,
    int* __restrict__ off, const int* __restrict__ boff, int* __restrict__ cur)
{
    int i = blockIdx.x * 256 + threadIdx.x;
    if (i < NN) {
        int incl = off[i + 1] + boff[blockIdx.x];
        off[i + 1] = incl;
        cur[i] = incl - cnt[i];
    }
    if (i == 0) off[0] = 0;
}

// ---- merged: blocks [0,2048): fused scatter+convert (64B records);
// blocks [2048,3072): aggr = (1+eps[0]) * x  (independent work, deps satisfied)
__global__ __launch_bounds__(256) void k_scatter2(
    const int* __restrict__ src, const int* __restrict__ dst,
    int* __restrict__ cur, const float* __restrict__ ea,
    unsigned short* __restrict__ eaz,
    const float* __restrict__ x, const float* __restrict__ eps,
    float* __restrict__ aggr)
{
    int t = threadIdx.x;
    if (blockIdx.x >= 2048) {
        int tid = (blockIdx.x - 2048) * 256 + t;
        float sc = 1.f + eps[0];
        const float4* xv = (const float4*)x;
        float4* av = (float4*)aggr;
        for (int i = tid; i < NN * 16; i += 1024 * 256) {
            float4 v = xv[i];
            v.x *= sc; v.y *= sc; v.z *= sc; v.w *= sc;
            av[i] = v;
        }
        return;
    }
    int tid = blockIdx.x * 256 + t;
    for (int e = tid; e < NE; e += 2048 * 256) {
        int s = src[e], d = dst[e];
        int p = atomicAdd(&cur[d], 1);
        const float4* ap = (const float4*)(ea + (size_t)e * 16);
        float4 a0 = ap[0], a1 = ap[1], a2 = ap[2], a3 = ap[3];
        float v[16] = {a0.x, a0.y, a0.z, a0.w, a1.x, a1.y, a1.z, a1.w,
                       a2.x, a2.y, a2.z, a2.w, a3.x, a3.y, a3.z, a3.w};
        unsigned hi[8], lo[6];
        #pragma unroll
        for (int j = 0; j < 8; ++j) {
            unsigned short h0 = f2bf(v[2 * j]), h1 = f2bf(v[2 * j + 1]);
            hi[j] = (unsigned)h0 | ((unsigned)h1 << 16);
            if (j < 6)
                lo[j] = (unsigned)f2bf(v[2 * j] - bf2f(h0))
                      | ((unsigned)f2bf(v[2 * j + 1] - bf2f(h1)) << 16);
        }
        uint4* rec = (uint4*)(eaz + (size_t)p * 32);
        uint4 r0 = {hi[0], hi[1], hi[2], hi[3]};
        uint4 r1 = {hi[4], hi[5], hi[6], hi[7]};
        uint4 r2 = {lo[0], lo[1], lo[2], lo[3]};
        uint4 r3 = {lo[4], lo[5], (unsigned)s, (unsigned)d};
        rec[0] = r0; rec[1] = r1; rec[2] = r2; rec[3] = r3;
    }
}

// ---- MFMA edge aggregation: wave owns 8 chunks x 16 sorted edges.
__global__ __launch_bounds__(256) void k_aggr_m(
    const float* __restrict__ x, const unsigned short* __restrict__ eaz,
    const float* __restrict__ We, const float* __restrict__ be,
    float* __restrict__ aggr)
{
    __shared__ unsigned short wth[1024], wtl[1024];  // [col][k] transposed We hi/lo
    __shared__ float els[4 * 16 * 65];               // per-wave e' tile [16 edges][65]
    int t = threadIdx.x;
    for (int i = t; i < 1024; i += 256) {
        int col = i >> 4, k = i & 15;
        float v = We[k * 64 + col];
        unsigned short h = f2bf(v);
        wth[col * 16 + k] = h;
        wtl[col * 16 + k] = f2bf(v - bf2f(h));
    }
    __syncthreads();

    int lane = t & 63, w = t >> 6;
    float* myels = els + w * (16 * 65);
    int ar = lane & 15;
    int kg = (lane >> 4) & 1;
    bool klive = lane < 32;

    bf16x8 bh[4], bl[4];
    float bias4[4];
    #pragma unroll
    for (int nc = 0; nc < 4; ++nc) {
        int col = nc * 16 + ar;
        uint4 hv = {0, 0, 0, 0}, lv = {0, 0, 0, 0};
        if (klive) {
            hv = *(const uint4*)(wth + col * 16 + kg * 8);
            lv = *(const uint4*)(wtl + col * 16 + kg * 8);
        }
        bh[nc] = u4_to_bf(hv);
        bl[nc] = u4_to_bf(lv);
        bias4[nc] = be[col];
    }

    int cbase0 = (blockIdx.x * 4 + w) * 8;
    for (int ci = 0; ci < 8; ++ci) {
        int chunk = cbase0 + ci;
        if (chunk >= NCHUNK) break;
        int e0 = chunk * 16;
        const unsigned short* rec = eaz + (size_t)(e0 + ar) * 32;

        // src/dst live in the record tail (same 64B line as fragments)
        int2 sdv = *(const int2*)(rec + 28);
        int sl = sdv.x, dl = sdv.y;

        uint4 hv = {0, 0, 0, 0}, lv = {0, 0, 0, 0};
        if (klive) {
            hv = *(const uint4*)(rec + kg * 8);
            lv = *(const uint4*)(rec + 16 + kg * 8);
            if (kg) { lv.z = 0; lv.w = 0; }  // tail words hold src/dst, not lo
        }
        bf16x8 ah = u4_to_bf(hv), al = u4_to_bf(lv);

        float xv[16];
        #pragma unroll
        for (int e = 0; e < 16; ++e) {
            int s_e = __builtin_amdgcn_readlane(sl, e);
            xv[e] = x[(size_t)s_e * 64 + lane];
        }

        #pragma unroll
        for (int nc = 0; nc < 4; ++nc) {
            f32x4 acc;
            acc[0] = bias4[nc]; acc[1] = bias4[nc]; acc[2] = bias4[nc]; acc[3] = bias4[nc];
            acc = __builtin_amdgcn_mfma_f32_16x16x32_bf16(ah, bh[nc], acc, 0, 0, 0);
            acc = __builtin_amdgcn_mfma_f32_16x16x32_bf16(al, bh[nc], acc, 0, 0, 0);
            acc = __builtin_amdgcn_mfma_f32_16x16x32_bf16(ah, bl[nc], acc, 0, 0, 0);
            int rbase = (lane >> 4) * 4;
            #pragma unroll
            for (int r = 0; r < 4; ++r)
                myels[(rbase + r) * 65 + nc * 16 + ar] = acc[r];
        }

        int d = __builtin_amdgcn_readlane(dl, 0);
        float acc = 0.f;
        #pragma unroll
        for (int e = 0; e < 16; ++e) {
            float m = xv[e] + myels[e * 65 + lane];
            m = fmaxf(m, 0.f);
            acc += m;
            int dn = (e < 15) ? __builtin_amdgcn_readlane(dl, e + 1) : -1;
            if (dn != d) {
                atomicAdd(&aggr[(size_t)d * 64 + lane], acc);
                acc = 0.f;
                d = dn;
            }
        }
    }
}

// ---- split-bf16 MFMA [N,64]@Wt+b. PRE: BN+lrelu input. POST0: raw+stats. POST1: lrelu (+pool).
template<int PRE, int POST>
__global__ __launch_bounds__(256) void k_mm64_f(
    const float* __restrict__ in,
    const unsigned short* __restrict__ Wh, const unsigned short* __restrict__ Wl,
    const float* __restrict__ bias, const float* __restrict__ statsIn,
    const float* __restrict__ gIn, const float* __restrict__ bIn,
    float* __restrict__ out, float* __restrict__ statsOut,
    const int* __restrict__ batch, float* __restrict__ pool)
{
    __shared__ unsigned short Ash[64 * 64], Asl[64 * 64];
    __shared__ unsigned short Bsh[64 * 64], Bsl[64 * 64];
    __shared__ float sc[64], sh[64];
    __shared__ float red[4 * 128];
    int t = threadIdx.x;
    int base = blockIdx.x * 64;
    if (PRE && t < 64) {
        float m = statsIn[t] * (1.f / NN);
        float v = statsIn[64 + t] * (1.f / NN) - m * m;
        float s = gIn[t] * rsqrtf(v + BN_EPS);
        sc[t] = s; sh[t] = bIn[t] - m * s;
    }
    for (int i = t; i < 512; i += 256) {
        int n = i >> 3, cb = i & 7;
        ((uint4*)Bsh)[n * 8 + (cb ^ (n & 7))] = ((const uint4*)Wh)[i];
        ((uint4*)Bsl)[n * 8 + (cb ^ (n & 7))] = ((const uint4*)Wl)[i];
    }
    __syncthreads();
    for (int i = t; i < 512; i += 256) {
        int row = i >> 3, cb = i & 7;
        int node = base + row;
        float v[8] = {0.f, 0.f, 0.f, 0.f, 0.f, 0.f, 0.f, 0.f};
        if (node < NN) {
            float4 u0 = *(const float4*)(in + (size_t)node * 64 + cb * 8);
            float4 u1 = *(const float4*)(in + (size_t)node * 64 + cb * 8 + 4);
            v[0] = u0.x; v[1] = u0.y; v[2] = u0.z; v[3] = u0.w;
            v[4] = u1.x; v[5] = u1.y; v[6] = u1.z; v[7] = u1.w;
            if (PRE) {
                #pragma unroll
                for (int j = 0; j < 8; ++j) {
                    int c = cb * 8 + j;
                    v[j] = lrelu(fmaf(v[j], sc[c], sh[c]));
                }
            }
        }
        unsigned hw[4], lw[4];
        #pragma unroll
        for (int j = 0; j < 4; ++j) {
            unsigned short h0 = f2bf(v[2 * j]), h1 = f2bf(v[2 * j + 1]);
            unsigned short l0 = f2bf(v[2 * j] - bf2f(h0)), l1 = f2bf(v[2 * j + 1] - bf2f(h1));
            hw[j] = (unsigned)h0 | ((unsigned)h1 << 16);
            lw[j] = (unsigned)l0 | ((unsigned)l1 << 16);
        }
        uint4 rh = { hw[0], hw[1], hw[2], hw[3] };
        uint4 rl = { lw[0], lw[1], lw[2], lw[3] };
        int idx = row * 8 + (cb ^ (row & 7));
        ((uint4*)Ash)[idx] = rh;
        ((uint4*)Asl)[idx] = rl;
    }
    __syncthreads();

    int w = t >> 6, l = t & 63;
    int ar = l & 15, kg = l >> 4;
    bf16x8 afh[2], afl[2];
    #pragma unroll
    for (int kt = 0; kt < 2; ++kt) {
        int row = w * 16 + ar, cb = kt * 4 + kg;
        int idx = row * 8 + (cb ^ (row & 7));
        afh[kt] = ((const bf16x8*)Ash)[idx];
        afl[kt] = ((const bf16x8*)Asl)[idx];
    }
    f32x4 acc[4];
    #pragma unroll
    for (int nt = 0; nt < 4; ++nt) { acc[nt][0] = 0.f; acc[nt][1] = 0.f; acc[nt][2] = 0.f; acc[nt][3] = 0.f; }
    #pragma unroll
    for (int nt = 0; nt < 4; ++nt) {
        #pragma unroll
        for (int kt = 0; kt < 2; ++kt) {
            int n = nt * 16 + ar, cb = kt * 4 + kg;
            int idx = n * 8 + (cb ^ (n & 7));
            bf16x8 bfh = ((const bf16x8*)Bsh)[idx];
            bf16x8 bfl = ((const bf16x8*)Bsl)[idx];
            acc[nt] = __builtin_amdgcn_mfma_f32_16x16x32_bf16(afh[kt], bfh, acc[nt], 0, 0, 0);
            acc[nt] = __builtin_amdgcn_mfma_f32_16x16x32_bf16(afl[kt], bfh, acc[nt], 0, 0, 0);
            acc[nt] = __builtin_amdgcn_mfma_f32_16x16x32_bf16(afh[kt], bfl, acc[nt], 0, 0, 0);
        }
    }
    int rb = base + w * 16 + kg * 4;
    int bidx[4];
    if (POST == 1) {
        #pragma unroll
        for (int r = 0; r < 4; ++r)
            bidx[r] = (rb + r < NN) ? batch[rb + r] : 0;
    }
    #pragma unroll
    for (int nt = 0; nt < 4; ++nt) {
        int col = nt * 16 + ar;
        float bv = bias[col];
        float s = 0.f, q = 0.f;
        #pragma unroll
        for (int r = 0; r < 4; ++r) {
            int node = rb + r;
            float d = acc[nt][r] + bv;
            if (POST == 1) d = lrelu(d);
            if (node < NN) {
                out[(size_t)node * 64 + col] = d;
                if (POST == 1)
                    atomicAdd(&pool[(size_t)bidx[r] * 64 + col], d);
            }
            if (POST == 0) {
                d = (node < NN) ? d : 0.f;
                s += d; q += d * d;
            }
        }
        if (POST == 0) {
            s += __shfl_xor(s, 16); s += __shfl_xor(s, 32);
            q += __shfl_xor(q, 16); q += __shfl_xor(q, 32);
            if (kg == 0) { red[w * 128 + col] = s; red[w * 128 + 64 + col] = q; }
        }
    }
    if (POST == 0) {
        __syncthreads();
        if (t < 128) {
            int c = t & 63, which = t >> 6;
            float v = red[0 * 128 + which * 64 + c] + red[1 * 128 + which * 64 + c]
                    + red[2 * 128 + which * 64 + c] + red[3 * 128 + which * 64 + c];
            atomicAdd(&statsOut[which * 64 + c], v);
        }
    }
}

// ---- split-bf16 MFMA [N,128]@Wt+b, 64-col blocks.
template<int MODE>
__global__ __launch_bounds__(256) void k_cmm_f(
    const float* __restrict__ inA, const float* __restrict__ pool,
    const int* __restrict__ batch, const float* __restrict__ statsIn,
    const float* __restrict__ gIn, const float* __restrict__ bIn,
    const unsigned short* __restrict__ Wh, const unsigned short* __restrict__ Wl,
    const float* __restrict__ bias,
    float* __restrict__ out, float* __restrict__ statsOut)
{
    __shared__ unsigned short Ash[64 * 128], Asl[64 * 128];
    __shared__ unsigned short Bsh[64 * 128], Bsl[64 * 128];
    __shared__ float sc[128], sh[128];
    __shared__ float red[4 * 128];
    int t = threadIdx.x;
    int base = (blockIdx.x >> 1) * 64;
    int ncol0 = (blockIdx.x & 1) * 64;
    if (MODE == 1 && t < 128) {
        float m = statsIn[t] * (1.f / NN);
        float v = statsIn[128 + t] * (1.f / NN) - m * m;
        float s = gIn[t] * rsqrtf(v + BN_EPS);
        sc[t] = s; sh[t] = bIn[t] - m * s;
    }
    for (int i = t; i < 1024; i += 256) {
        int n = i >> 4, cb = i & 15;
        int idx = n * 16 + (cb ^ (n & 7));
        ((uint4*)Bsh)[idx] = ((const uint4*)Wh)[(ncol0 + n) * 16 + cb];
        ((uint4*)Bsl)[idx] = ((const uint4*)Wl)[(ncol0 + n) * 16 + cb];
    }
    __syncthreads();
    for (int i = t; i < 1024; i += 256) {
        int row = i >> 4, cb = i & 15;
        int node = base + row;
        float v[8] = {0.f, 0.f, 0.f, 0.f, 0.f, 0.f, 0.f, 0.f};
        if (node < NN) {
            const float* sp;
            if (MODE == 0) {
                sp = (cb < 8) ? (inA + (size_t)node * 64 + cb * 8)
                              : (pool + (size_t)batch[node] * 64 + (cb - 8) * 8);
            } else {
                sp = inA + (size_t)node * 128 + cb * 8;
            }
            float4 u0 = *(const float4*)sp;
            float4 u1 = *(const float4*)(sp + 4);
            v[0] = u0.x; v[1] = u0.y; v[2] = u0.z; v[3] = u0.w;
            v[4] = u1.x; v[5] = u1.y; v[6] = u1.z; v[7] = u1.w;
            if (MODE == 1) {
                #pragma unroll
                for (int j = 0; j < 8; ++j) {
                    int c = cb * 8 + j;
                    v[j] = lrelu(fmaf(v[j], sc[c], sh[c]));
                }
            }
        }
        unsigned hw[4], lw[4];
        #pragma unroll
        for (int j = 0; j < 4; ++j) {
            unsigned short h0 = f2bf(v[2 * j]), h1 = f2bf(v[2 * j + 1]);
            unsigned short l0 = f2bf(v[2 * j] - bf2f(h0)), l1 = f2bf(v[2 * j + 1] - bf2f(h1));
            hw[j] = (unsigned)h0 | ((unsigned)h1 << 16);
            lw[j] = (unsigned)l0 | ((unsigned)l1 << 16);
        }
        uint4 rh = { hw[0], hw[1], hw[2], hw[3] };
        uint4 rl = { lw[0], lw[1], lw[2], lw[3] };
        int idx = row * 16 + (cb ^ (row & 7));
        ((uint4*)Ash)[idx] = rh;
        ((uint4*)Asl)[idx] = rl;
    }
    __syncthreads();

    int w = t >> 6, l = t & 63;
    int ar = l & 15, kg = l >> 4;
    bf16x8 afh[4], afl[4];
    #pragma unroll
    for (int kt = 0; kt < 4; ++kt) {
        int row = w * 16 + ar, cb = kt * 4 + kg;
        int idx = row * 16 + (cb ^ (row & 7));
        afh[kt] = ((const bf16x8*)Ash)[idx];
        afl[kt] = ((const bf16x8*)Asl)[idx];
    }
    f32x4 acc[4];
    #pragma unroll
    for (int nt = 0; nt < 4; ++nt) { acc[nt][0] = 0.f; acc[nt][1] = 0.f; acc[nt][2] = 0.f; acc[nt][3] = 0.f; }
    #pragma unroll
    for (int nt = 0; nt < 4; ++nt) {
        #pragma unroll
        for (int kt = 0; kt < 4; ++kt) {
            int n = nt * 16 + ar, cb = kt * 4 + kg;
            int idx = n * 16 + (cb ^ (n & 7));
            bf16x8 bfh = ((const bf16x8*)Bsh)[idx];
            bf16x8 bfl = ((const bf16x8*)Bsl)[idx];
            acc[nt] = __builtin_amdgcn_mfma_f32_16x16x32_bf16(afh[kt], bfh, acc[nt], 0, 0, 0);
            acc[nt] = __builtin_amdgcn_mfma_f32_16x16x32_bf16(afl[kt], bfh, acc[nt], 0, 0, 0);
            acc[nt] = __builtin_amdgcn_mfma_f32_16x16x32_bf16(afh[kt], bfl, acc[nt], 0, 0, 0);
        }
    }
    int rb = base + w * 16 + kg * 4;
    #pragma unroll
    for (int nt = 0; nt < 4; ++nt) {
        int colg = ncol0 + nt * 16 + ar;
        float bv = bias[colg];
        float s = 0.f, q = 0.f;
        #pragma unroll
        for (int r = 0; r < 4; ++r) {
            int node = rb + r;
            float d = acc[nt][r] + bv;
            if (node < NN) out[(size_t)node * 128 + colg] = d;
            d = (node < NN) ? d : 0.f;
            s += d; q += d * d;
        }
        s += __shfl_xor(s, 16); s += __shfl_xor(s, 32);
        q += __shfl_xor(q, 16); q += __shfl_xor(q, 32);
        int col = nt * 16 + ar;
        if (kg == 0) { red[w * 128 + col] = s; red[w * 128 + 64 + col] = q; }
    }
    __syncthreads();
    if (t < 128) {
        int c = t & 63, which = t >> 6;
        float v = red[0 * 128 + which * 64 + c] + red[1 * 128 + which * 64 + c]
                + red[2 * 128 + which * 64 + c] + red[3 * 128 + which * 64 + c];
        atomicAdd(&statsOut[which * 128 + ncol0 + c], v);
    }
}

// ---- fused: x = lrelu(bn(h)); aggrOut = (1+eps[nextLayer]) * x
__global__ __launch_bounds__(256) void k_bn2(
    const float* __restrict__ in, const float* __restrict__ stats,
    const float* __restrict__ g, const float* __restrict__ b,
    const float* __restrict__ eps, int nextLayer,
    float* __restrict__ xout, float* __restrict__ aggrOut)
{
    int tid = blockIdx.x * 256 + threadIdx.x;
    float e1 = 1.f + eps[nextLayer];
    for (int i = tid; i < NN * 16; i += gridDim.x * 256) {
        int c4 = (i & 15) << 2;
        float4 v = ((const float4*)in)[i];
        float o[4] = {v.x, v.y, v.z, v.w};
        #pragma unroll
        for (int j = 0; j < 4; ++j) {
            int c = c4 + j;
            float m = stats[c] * (1.f / NN);
            float vv = stats[64 + c] * (1.f / NN) - m * m;
            float s = g[c] * rsqrtf(vv + BN_EPS);
            o[j] = lrelu(fmaf(o[j] - m, s, b[c]));
        }
        float4 r = {o[0], o[1], o[2], o[3]};
        ((float4*)xout)[i] = r;
        float4 r2 = {o[0] * e1, o[1] * e1, o[2] * e1, o[3] * e1};
        ((float4*)aggrOut)[i] = r2;
    }
}

// ---- out[n] = lrelu(bn(h128[n])) . cW3 + cb3
__global__ __launch_bounds__(256) void k_out(
    const float* __restrict__ h, const float* __restrict__ stats,
    const float* __restrict__ g, const float* __restrict__ b,
    const float* __restrict__ W3, const float* __restrict__ b3,
    float* __restrict__ outv)
{
    int lane = threadIdx.x & 63;
    int wid = (blockIdx.x * 256 + threadIdx.x) >> 6;
    int nw = (gridDim.x * 256) >> 6;
    float m0 = stats[lane] * (1.f / NN);
    float v0 = stats[128 + lane] * (1.f / NN) - m0 * m0;
    float s0 = g[lane] * rsqrtf(v0 + BN_EPS);
    float h0 = b[lane] - m0 * s0;
    float m1 = stats[64 + lane] * (1.f / NN);
    float v1 = stats[128 + 64 + lane] * (1.f / NN) - m1 * m1;
    float s1 = g[64 + lane] * rsqrtf(v1 + BN_EPS);
    float h1 = b[64 + lane] - m1 * s1;
    float w0 = W3[lane], w1 = W3[64 + lane];
    float bb = b3[0];
    for (int n = wid; n < NN; n += nw) {
        float a = h[(size_t)n * 128 + lane];
        float c = h[(size_t)n * 128 + 64 + lane];
        a = lrelu(fmaf(a, s0, h0));
        c = lrelu(fmaf(c, s1, h1));
        float p = a * w0 + c * w1;
        p += __shfl_xor(p, 32);
        p += __shfl_xor(p, 16);
        p += __shfl_xor(p, 8);
        p += __shfl_xor(p, 4);
        p += __shfl_xor(p, 2);
        p += __shfl_xor(p, 1);
        if (lane == 0) outv[n] = p + bb;
    }
}

extern "C" void kernel_launch(void* const* d_in, const int* in_sizes, int n_in,
                              void* d_out, int out_size, void* d_ws, size_t ws_size,
                              hipStream_t stream)
{
    const float* x0   = (const float*)d_in[0];
    const float* ea   = (const float*)d_in[1];
    const float* leW  = (const float*)d_in[2];
    const float* leb  = (const float*)d_in[3];
    const float* W1   = (const float*)d_in[4];
    const float* b1   = (const float*)d_in[5];
    const float* g1   = (const float*)d_in[6];
    const float* bb1  = (const float*)d_in[7];
    const float* W2   = (const float*)d_in[8];
    const float* b2   = (const float*)d_in[9];
    const float* eps  = (const float*)d_in[10];
    const float* og   = (const float*)d_in[11];
    const float* ob   = (const float*)d_in[12];
    const float* cW1  = (const float*)d_in[13];
    const float* cb1  = (const float*)d_in[14];
    const float* cg1  = (const float*)d_in[15];
    const float* cbb1 = (const float*)d_in[16];
    const float* cW2  = (const float*)d_in[17];
    const float* cb2  = (const float*)d_in[18];
    const float* cg2  = (const float*)d_in[19];
    const float* cbb2 = (const float*)d_in[20];
    const float* cW3  = (const float*)d_in[21];
    const float* cb3  = (const float*)d_in[22];
    const int* ei     = (const int*)d_in[23];
    const int* batch  = (const int*)d_in[24];
    const int* src = ei;
    const int* dst = ei + NE;

    // ---- workspace layout (4-byte units). eaz aliases h128 (disjoint lifetimes).
    float* xbuf   = (float*)d_ws;                       // NN*64
    float* hbuf   = xbuf + (size_t)NN * 64;             // NN*64
    unsigned short* eaz = (unsigned short*)(hbuf + (size_t)NN * 64); // NE*32 ushort (64B/edge)
    float* h128   = (float*)eaz;                        // NN*128 (head) — alias
    float* pool   = (float*)(eaz + (size_t)NE * 32);    // NG*64
    float* cstats = pool + (size_t)NG * 64;             // 512
    float* stats  = cstats + 512;                       // 768 (3 x 256)
    int*   cnt    = (int*)(stats + 768);                // NN
    int*   off    = cnt + NN;                           // NN+1 (+pad)
    int*   cur    = off + NN + 4;                       // NN
    int*   bsum   = cur + NN;                           // 256
    int*   boff   = bsum + 256;                         // 256
    unsigned short* w1h  = (unsigned short*)(boff + 256); // 3*4096 each
    unsigned short* w1l  = w1h + 3 * 4096;
    unsigned short* w2h  = w1l + 3 * 4096;
    unsigned short* w2l  = w2h + 3 * 4096;
    unsigned short* cw1h = w2l + 3 * 4096;              // 16384 each
    unsigned short* cw1l = cw1h + 16384;
    unsigned short* cw2h = cw1l + 16384;
    unsigned short* cw2l = cw2h + 16384;
    float* outp   = (float*)d_out;

    int zeroN = NG * 64 + 512 + 768 + NN;  // pool..cnt contiguous

    int fGrid  = (NN + 63) / 64;            // 782 (MFMA GEMMs)
    int aGrid  = (NCHUNK + 31) / 32;        // 1563 (k_aggr_m: 32 chunks/block)

    // ---- one-time: setup (zero + wcvt), hist (after zero), CSR scans, scatter+init
    k_setup<<<520, 256, 0, stream>>>((int*)pool, zeroN, W1, W2, cW1, cW2,
                                     w1h, w1l, w2h, w2l, cw1h, cw1l, cw2h, cw2l);
    k_hist<<<1024, 256, 0, stream>>>(dst, cnt);
    k_scanA<<<NB_SCAN, 256, 0, stream>>>(cnt, off, bsum);
    k_scanB<<<1, 256, 0, stream>>>(bsum, boff);
    k_scanC<<<NB_SCAN, 256, 0, stream>>>(cnt, off, boff, cur);
    k_scatter2<<<3072, 256, 0, stream>>>(src, dst, cur, ea, eaz, x0, eps, hbuf);

    for (int l = 0; l < 3; ++l) {
        const float* xc = (l == 0) ? x0 : xbuf;
        float* st = stats + l * 256;
        k_aggr_m<<<aGrid, 256, 0, stream>>>(xc, eaz,
                leW + l * 1024, leb + l * 64, hbuf);
        k_mm64_f<0, 0><<<fGrid, 256, 0, stream>>>(hbuf, w1h + l * 4096, w1l + l * 4096,
                b1 + l * 64, nullptr, nullptr, nullptr, hbuf, st, nullptr, nullptr);
        if (l < 2) {
            k_mm64_f<1, 0><<<fGrid, 256, 0, stream>>>(hbuf, w2h + l * 4096, w2l + l * 4096,
                    b2 + l * 64, st, g1 + l * 64, bb1 + l * 64, hbuf, st + 128,
                    nullptr, nullptr);
            k_bn2<<<1024, 256, 0, stream>>>(hbuf, st + 128, og + l * 64, ob + l * 64,
                    eps, l + 1, xbuf, hbuf);
        } else {
            k_mm64_f<1, 1><<<fGrid, 256, 0, stream>>>(hbuf, w2h + l * 4096, w2l + l * 4096,
                    b2 + l * 64, st, g1 + l * 64, bb1 + l * 64, xbuf, nullptr,
                    batch, pool);
        }
    }
    k_cmm_f<0><<<fGrid * 2, 256, 0, stream>>>(xbuf, pool, batch, nullptr, nullptr, nullptr,
                                              cw1h, cw1l, cb1, h128, cstats);
    k_cmm_f<1><<<fGrid * 2, 256, 0, stream>>>(h128, nullptr, nullptr, cstats, cg1, cbb1,
                                              cw2h, cw2l, cb2, h128, cstats + 256);
    k_out<<<1024, 256, 0, stream>>>(h128, cstats + 256, cg2, cbb2, cW3, cb3, outp);
}